// Round 9
// baseline (1165.010 us; speedup 1.0000x reference)
//
#include <hip/hip_runtime.h>
#include <math.h>

#define Bsz 16
#define Tt 24
#define Nn 256
#define Fp 6
#define Hh 64
#define PredL 12
#define Fw 4
#define M1 32
#define TCHUNK 12
#define DEG2RAD 0.017453292519943295f
#define IDX2(t, b) ((t) * Bsz + (b))

// ---------------------------------------------------------------------------
// P0+PT: blocks 0..255 build packed pk[i][j] = {Ac,As}; block 256 repacks
// weights (wgc2T[k][g], wm1T, wm2T, wihP/whhP float4 {r,z,n,0} per [k][lane]).
// ---------------------------------------------------------------------------
__global__ __launch_bounds__(256) void k_prep(
    const float* __restrict__ coords, const float* __restrict__ adj,
    const float* __restrict__ wgc2, const float* __restrict__ wih,
    const float* __restrict__ whh,  const float* __restrict__ wm1,
    const float* __restrict__ wm2,
    float2* __restrict__ pk,
    float* __restrict__ wgc2T, float* __restrict__ wm1T, float* __restrict__ wm2T,
    float4* __restrict__ wihP, float4* __restrict__ whhP) {
  int tid = threadIdx.x;
  if (blockIdx.x < Nn) {
    int i = blockIdx.x;
    int j = tid;
    float dx = coords[2 * j]     - coords[2 * i];
    float dy = coords[2 * j + 1] - coords[2 * i + 1];
    float ang = atan2f(dy, dx);
    float a = adj[i * Nn + j];
    pk[i * Nn + j] = make_float2(a * cosf(ang), a * sinf(ang));
    return;
  }
  for (int idx = tid; idx < Hh * Hh; idx += 256) {
    int g = idx / Hh, k = idx % Hh;
    wgc2T[k * Hh + g] = wgc2[g * Hh + k];
  }
  for (int idx = tid; idx < M1 * Hh; idx += 256) {
    int m = idx / Hh, k = idx % Hh;
    wm1T[k * M1 + m] = wm1[m * Hh + k];
  }
  for (int idx = tid; idx < Fp * M1; idx += 256) {
    int f = idx / M1, m = idx % M1;
    wm2T[m * Fp + f] = wm2[f * M1 + m];
  }
  for (int idx = tid; idx < Hh * 64; idx += 256) {
    int k = idx >> 6, lane = idx & 63;
    wihP[idx] = make_float4(wih[(0 * 64 + lane) * Hh + k],
                            wih[(1 * 64 + lane) * Hh + k],
                            wih[(2 * 64 + lane) * Hh + k], 0.f);
    whhP[idx] = make_float4(whh[(0 * 64 + lane) * Hh + k],
                            whh[(1 * 64 + lane) * Hh + k],
                            whh[(2 * 64 + lane) * Hh + k], 0.f);
  }
}

// ---------------------------------------------------------------------------
// E: fused encoder: deg + gconv1 + gconv2 + W2 -> sf_all. One block per (t,b).
// Pass-2 = round-6 structure (thread=row, z[64] regs, LDS b128 broadcasts).
// ---------------------------------------------------------------------------
__global__ __launch_bounds__(256) void k_enc(
    const float2* __restrict__ pk, const float* __restrict__ hp,
    const float* __restrict__ hw,
    const float* __restrict__ wgc1, const float* __restrict__ bgc1,
    const float* __restrict__ wgc2T, const float* __restrict__ bgc2,
    float* __restrict__ sf_all,
    float* __restrict__ d23, float* __restrict__ e23) {
  __shared__ float d_lds[Nn];
  __shared__ float e_lds[Nn];
  __shared__ __align__(16) float u_s[Nn * 8];     // 8KB
  __shared__ __align__(16) float h1_s[Nn * 68];   // 69.6KB
  int tb = blockIdx.x, t = tb / Bsz, b = tb % Bsz;
  int tid = threadIdx.x;
  int i = tid;
  float spd = hw[(b * Tt + t) * Fw + 2];
  float rad = hw[(b * Tt + t) * Fw + 1] * DEG2RAD;
  float scr = spd * cosf(rad), ssr = spd * sinf(rad);

  // ---- pass 0: degrees (from column i of pk) ----
  {
    float rs = 0.f, cs = 0.f;
#pragma unroll 4
    for (int j = 0; j < Nn; ++j) {
      float2 pv = pk[j * Nn + i];
      float v = pv.x * scr + pv.y * ssr;   // V(j,i)
      cs += fmaxf(v, 0.f);
      rs += fmaxf(-v, 0.f);
    }
    float2 pd = pk[i * Nn + i];
    float vii = pd.x * scr + pd.y * ssr;
    rs += vii;  // diag fix
    float di = 1.f / (sqrtf(rs + 1.f) + 1e-6f);
    float ei = 1.f / (sqrtf(cs + 1.f) + 1e-6f);
    d_lds[i] = di; e_lds[i] = ei;
    if (t == Tt - 1) { d23[b * Nn + i] = di; e23[b * Nn + i] = ei; }
  }
  __syncthreads();

  // ---- stage u = d_j * x ----
  {
    const float* xsrc = hp + (long)(b * Tt + t) * Nn * Fp;
    for (int idx = tid; idx < Nn * Fp; idx += 256) {
      int j = idx / Fp, f = idx - j * Fp;
      u_s[j * 8 + f] = d_lds[j] * xsrc[idx];
    }
    u_s[tid * 8 + 6] = 0.f;
    u_s[tid * 8 + 7] = 0.f;
  }
  __syncthreads();

  // ---- pass 1: gconv1 for row i; e-scaled h1 row -> LDS ----
  {
    float a0 = 0.f, a1 = 0.f, a2 = 0.f, a3 = 0.f, a4 = 0.f, a5 = 0.f;
#pragma unroll 2
    for (int j = 0; j < Nn; ++j) {
      float2 pv = pk[j * Nn + i];
      float v = pv.x * scr + pv.y * ssr;
      float w = fmaxf(-v, 0.f);            // wout[i][j], wrong on diag
      float4 ul = *(const float4*)&u_s[j * 8];
      float4 uh = *(const float4*)&u_s[j * 8 + 4];
      a0 += w * ul.x; a1 += w * ul.y; a2 += w * ul.z;
      a3 += w * ul.w; a4 += w * uh.x; a5 += w * uh.y;
    }
    float2 pd = pk[i * Nn + i];
    float vii = pd.x * scr + pd.y * ssr;
    float di = d_lds[i], ei = e_lds[i];
    float c1 = vii + 1.f;  // diag fix + identity
    float y0 = di * (a0 + c1 * u_s[i * 8 + 0]);
    float y1 = di * (a1 + c1 * u_s[i * 8 + 1]);
    float y2 = di * (a2 + c1 * u_s[i * 8 + 2]);
    float y3 = di * (a3 + c1 * u_s[i * 8 + 3]);
    float y4 = di * (a4 + c1 * u_s[i * 8 + 4]);
    float y5 = di * (a5 + c1 * u_s[i * 8 + 5]);
#pragma unroll
    for (int g4 = 0; g4 < 16; ++g4) {
      float4 hv;
#pragma unroll
      for (int q = 0; q < 4; ++q) {
        int g = g4 * 4 + q;
        float v2 = bgc1[g] + wgc1[g * Fp + 0] * y0 + wgc1[g * Fp + 1] * y1 +
                   wgc1[g * Fp + 2] * y2 + wgc1[g * Fp + 3] * y3 +
                   wgc1[g * Fp + 4] * y4 + wgc1[g * Fp + 5] * y5;
        ((float*)&hv)[q] = fmaxf(v2, 0.f) * ei;
      }
      *(float4*)&h1_s[i * 68 + g4 * 4] = hv;
    }
  }
  __syncthreads();

  // ---- pass 2 (round-6 form): z[i][g] = e_i * sum_j (win+I)[i][j] h1e[j] ----
  float z[64];
#pragma unroll
  for (int k = 0; k < 64; ++k) z[k] = 0.f;
#pragma unroll 2
  for (int j = 0; j < Nn; ++j) {
    float2 pv = pk[j * Nn + i];
    float v = pv.x * scr + pv.y * ssr;     // V(j,i)
    float wf = fmaxf(v, 0.f) + ((j == i) ? 1.f : 0.f);
#pragma unroll
    for (int g4 = 0; g4 < 16; ++g4) {
      float4 h4 = *(const float4*)&h1_s[j * 68 + g4 * 4];
      z[g4 * 4 + 0] += wf * h4.x;
      z[g4 * 4 + 1] += wf * h4.y;
      z[g4 * 4 + 2] += wf * h4.z;
      z[g4 * 4 + 3] += wf * h4.w;
    }
  }
  {
    float ei = e_lds[i];
#pragma unroll
    for (int k = 0; k < 64; ++k) z[k] *= ei;
  }
  __syncthreads();   // h1_s free; reuse for sf staging

  // ---- W2 + relu -> staged in h1_s, then coalesced store ----
#pragma unroll
  for (int c = 0; c < 4; ++c) {
    float s[16];
#pragma unroll
    for (int q = 0; q < 16; ++q) s[q] = bgc2[c * 16 + q];
#pragma unroll
    for (int k = 0; k < 64; ++k) {
      float zk = z[k];
#pragma unroll
      for (int q = 0; q < 16; ++q) s[q] += wgc2T[k * Hh + c * 16 + q] * zk;
    }
#pragma unroll
    for (int q4 = 0; q4 < 4; ++q4) {
      float4 sv = make_float4(fmaxf(s[q4 * 4 + 0], 0.f), fmaxf(s[q4 * 4 + 1], 0.f),
                              fmaxf(s[q4 * 4 + 2], 0.f), fmaxf(s[q4 * 4 + 3], 0.f));
      *(float4*)&h1_s[i * 68 + c * 16 + q4 * 4] = sv;
    }
  }
  __syncthreads();
  long base = (long)IDX2(t, b) * Nn * Hh;
  for (int idx = tid; idx < Nn * 16; idx += 256) {
    int j = idx >> 4, g4 = idx & 15;
    *(float4*)&sf_all[base + j * Hh + g4 * 4] = *(const float4*)&h1_s[j * 68 + g4 * 4];
  }
}

// ---------------------------------------------------------------------------
// GI: gi = sf @ W_ih^T + b_ih for TCHUNK timesteps (16 rows/wave, VALU-bound)
// ---------------------------------------------------------------------------
__global__ __launch_bounds__(256) void k_gi(
    const float* __restrict__ sf_all, const float4* __restrict__ wihP,
    const float* __restrict__ bih, float* __restrict__ gi, int t0) {
  __shared__ float sf_c[4][16][64];
  int tid = threadIdx.x, w = tid >> 6, lane = tid & 63;
  int rowc0 = blockIdx.x * 64 + w * 16;
  long rowg0 = (long)t0 * (Bsz * Nn) + rowc0;
#pragma unroll
  for (int rr = 0; rr < 16; ++rr)
    sf_c[w][rr][lane] = sf_all[(rowg0 + rr) * Hh + lane];
  float bi_r = bih[lane], bi_z = bih[64 + lane], bi_n = bih[128 + lane];
  float ar[16], az[16], an[16];
#pragma unroll
  for (int rr = 0; rr < 16; ++rr) { ar[rr] = bi_r; az[rr] = bi_z; an[rr] = bi_n; }
#pragma unroll 2
  for (int kb = 0; kb < 16; ++kb) {
    int k0 = kb * 4;
    float4 wi0 = wihP[(k0 + 0) * 64 + lane];
    float4 wi1 = wihP[(k0 + 1) * 64 + lane];
    float4 wi2 = wihP[(k0 + 2) * 64 + lane];
    float4 wi3 = wihP[(k0 + 3) * 64 + lane];
#pragma unroll
    for (int rr = 0; rr < 16; ++rr) {
      const float4 s4 = *(const float4*)&sf_c[w][rr][k0];
      ar[rr] += s4.x * wi0.x + s4.y * wi1.x + s4.z * wi2.x + s4.w * wi3.x;
      az[rr] += s4.x * wi0.y + s4.y * wi1.y + s4.z * wi2.y + s4.w * wi3.y;
      an[rr] += s4.x * wi0.z + s4.y * wi1.z + s4.z * wi2.z + s4.w * wi3.z;
    }
  }
#pragma unroll
  for (int rr = 0; rr < 16; ++rr) {
    long rowc = rowc0 + rr;
    gi[(rowc * 3 + 0) * 64 + lane] = ar[rr];
    gi[(rowc * 3 + 1) * 64 + lane] = az[rr];
    gi[(rowc * 3 + 2) * 64 + lane] = an[rr];
  }
}

// ---------------------------------------------------------------------------
// GRU scan over one chunk (gh only; whh streamed; h broadcast via LDS rows)
// ---------------------------------------------------------------------------
__global__ __launch_bounds__(256) void k_gru_scan4(
    const float* __restrict__ gi, const float4* __restrict__ whhP,
    const float* __restrict__ bhh, float* __restrict__ hstate,
    int t0, int nt) {
  __shared__ float h_s[16][64];
  int b = blockIdx.x >> 4;
  int i0 = (blockIdx.x & 15) * 16;
  int tid = threadIdx.x, w = tid >> 6, lane = tid & 63;
  float bh_r = bhh[lane], bh_z = bhh[64 + lane], bh_n = bhh[128 + lane];
  float h_reg[4];
#pragma unroll
  for (int rr = 0; rr < 4; ++rr) {
    float hv = (t0 == 0) ? 0.f
                         : hstate[((long)b * Nn + i0 + w * 4 + rr) * Hh + lane];
    h_reg[rr] = hv;
    h_s[w * 4 + rr][lane] = hv;
  }
  for (int tl = 0; tl < nt; ++tl) {
    long rbase = ((long)tl * Bsz + b) * Nn + i0 + w * 4;
    float gr[4], gz[4], gn[4], hr[4], hz[4], hn[4];
#pragma unroll
    for (int rr = 0; rr < 4; ++rr) {
      gr[rr] = gi[((rbase + rr) * 3 + 0) * 64 + lane];
      gz[rr] = gi[((rbase + rr) * 3 + 1) * 64 + lane];
      gn[rr] = gi[((rbase + rr) * 3 + 2) * 64 + lane];
      hr[rr] = bh_r; hz[rr] = bh_z; hn[rr] = bh_n;
    }
#pragma unroll 4
    for (int kb = 0; kb < 16; ++kb) {
      int k0 = kb * 4;
      float4 wh0 = whhP[(k0 + 0) * 64 + lane];
      float4 wh1 = whhP[(k0 + 1) * 64 + lane];
      float4 wh2 = whhP[(k0 + 2) * 64 + lane];
      float4 wh3 = whhP[(k0 + 3) * 64 + lane];
#pragma unroll
      for (int rr = 0; rr < 4; ++rr) {
        const float4 h4 = *(const float4*)&h_s[w * 4 + rr][k0];
        hr[rr] += h4.x * wh0.x + h4.y * wh1.x + h4.z * wh2.x + h4.w * wh3.x;
        hz[rr] += h4.x * wh0.y + h4.y * wh1.y + h4.z * wh2.y + h4.w * wh3.y;
        hn[rr] += h4.x * wh0.z + h4.y * wh1.z + h4.z * wh2.z + h4.w * wh3.z;
      }
    }
#pragma unroll
    for (int rr = 0; rr < 4; ++rr) {
      float rg = 1.f / (1.f + expf(-(gr[rr] + hr[rr])));
      float zg = 1.f / (1.f + expf(-(gz[rr] + hz[rr])));
      float ng = tanhf(gn[rr] + rg * hn[rr]);
      float hv = (1.f - zg) * ng + zg * h_reg[rr];
      h_reg[rr] = hv;
      h_s[w * 4 + rr][lane] = hv;
    }
  }
#pragma unroll
  for (int rr = 0; rr < 4; ++rr)
    hstate[((long)b * Nn + i0 + w * 4 + rr) * Hh + lane] = h_reg[rr];
}

// ---------------------------------------------------------------------------
// MISC: blocks < Bsz*Nn: decoder adjacencies AT[i][j]=A1[j][i], A2d[i][j].
//       blocks >= Bsz*Nn: dec0 (x0 = mlp(h)).
// ---------------------------------------------------------------------------
__global__ __launch_bounds__(256) void k_misc(
    const float* __restrict__ hw, const float2* __restrict__ pk,
    const float* __restrict__ d23, const float* __restrict__ e23,
    float* __restrict__ AT, float* __restrict__ A2d,
    const float* __restrict__ hstate,
    const float* __restrict__ wm1T, const float* __restrict__ bm1,
    const float* __restrict__ wm2T, const float* __restrict__ bm2,
    float* __restrict__ xnext) {
  __shared__ float h_lds[16][Hh];
  __shared__ float u_lds[16][M1];
  int tid = threadIdx.x;
  if (blockIdx.x < Bsz * Nn) {
    int b = blockIdx.x >> 8;
    int i = blockIdx.x & 255;
    int j = tid;
    float spd = hw[(b * Tt + (Tt - 1)) * Fw + 2];
    float rad = hw[(b * Tt + (Tt - 1)) * Fw + 1] * DEG2RAD;
    float cr = cosf(rad), sr = sinf(rad);
    const float* drow = d23 + b * Nn;
    const float* erow = e23 + b * Nn;
    float2 pv = pk[i * Nn + j];
    float val = spd * (pv.x * cr + pv.y * sr);
    float dlt = (j == i) ? 1.f : 0.f;
    float wtji = (j == i) ? fmaxf(val, 0.f) : fmaxf(-val, 0.f);
    AT[((long)b * Nn + i) * Nn + j]  = drow[j] * (wtji + dlt) * drow[i];
    A2d[((long)b * Nn + i) * Nn + j] = erow[i] * (wtji + dlt) * erow[j];
    return;
  }
  int r0 = (blockIdx.x - Bsz * Nn) * 16;
#pragma unroll
  for (int c = 0; c < 4; ++c) {
    int idx = tid + c * 256;
    h_lds[idx >> 6][idx & 63] = hstate[(long)r0 * Hh + idx];
  }
  __syncthreads();
#pragma unroll
  for (int rep = 0; rep < 2; ++rep) {
    int idx = tid + rep * 256;
    int row = idx >> 5, m = idx & 31;
    float um = bm1[m];
    for (int k = 0; k < Hh; ++k) um += wm1T[k * M1 + m] * h_lds[row][k];
    u_lds[row][m] = fmaxf(um, 0.f);
  }
  __syncthreads();
  if (tid < 16 * Fp) {
    int row = tid / Fp, f = tid % Fp;
    float pf = bm2[f];
#pragma unroll
    for (int m = 0; m < M1; ++m) pf += wm2T[m * Fp + f] * u_lds[row][m];
    xnext[(r0 + row) * Fp + f] = pf;
  }
}

// ---------------------------------------------------------------------------
// Ddec fused: ONE kernel per decoder step. 128 blocks = 16 b x 8 groups of 32
// rows. Each block redundantly computes the FULL h1[256][64] in LDS (gconv1
// via AT), then agg (A2 rows via wave-uniform broadcast loads) + W2 + GRU +
// MLP block-locally. 108KB LDS, 1 block/CU.
// ---------------------------------------------------------------------------
__global__ __launch_bounds__(256) void k_dstep(
    const float* __restrict__ AT, const float* __restrict__ A2d,
    const float* __restrict__ xb_in, float* __restrict__ hstate,
    const float4* __restrict__ wihP, const float4* __restrict__ whhP,
    const float* __restrict__ wgc2T, const float* __restrict__ wgc1,
    const float* __restrict__ bgc1, const float* __restrict__ bgc2,
    const float* __restrict__ bih, const float* __restrict__ bhh,
    const float* __restrict__ wm1T, const float* __restrict__ bm1,
    const float* __restrict__ wm2T, const float* __restrict__ bm2,
    float* __restrict__ outp, float* __restrict__ xb_out, int p) {
  __shared__ __align__(16) float x_s[Nn * 8];     // 8KB
  __shared__ __align__(16) float y_s[Nn * 8];     // 8KB
  __shared__ float h1_s[Nn * Hh];                 // 64KB [j][g]
  __shared__ float z_s[32][Hh];                   // 8KB: z, then hn
  __shared__ float sf_s[32][Hh];                  // 8KB
  __shared__ float hp_s[32][Hh];                  // 8KB
  __shared__ float u_s2[32][M1];                  // 4KB

  int b = blockIdx.x >> 3;
  int i0 = (blockIdx.x & 7) * 32;
  int tid = threadIdx.x;
  int lane = tid & 63;
  int wu = __builtin_amdgcn_readfirstlane(tid >> 6);

  // ---- stage x (padded) and hprev (own rows) ----
  for (int idx = tid; idx < Nn * Fp; idx += 256) {
    int j = idx / Fp, f = idx - j * Fp;
    x_s[j * 8 + f] = xb_in[(long)b * Nn * Fp + idx];
  }
  x_s[tid * 8 + 6] = 0.f;
  x_s[tid * 8 + 7] = 0.f;
#pragma unroll
  for (int c = 0; c < 8; ++c) {
    int idx = tid + c * 256;
    hp_s[idx >> 6][idx & 63] = hstate[((long)b * Nn + i0) * Hh + idx];
  }
  __syncthreads();

  // ---- phase 1: y[i=tid] = sum_m AT[m][i] * x[m]  (all 256 rows) ----
  {
    float a0 = 0.f, a1 = 0.f, a2 = 0.f, a3 = 0.f, a4 = 0.f, a5 = 0.f;
    const float* atb = AT + (long)b * Nn * Nn;
#pragma unroll 4
    for (int m = 0; m < Nn; ++m) {
      float av = atb[m * Nn + tid];
      float4 xl = *(const float4*)&x_s[m * 8];
      float4 xh = *(const float4*)&x_s[m * 8 + 4];
      a0 += av * xl.x; a1 += av * xl.y; a2 += av * xl.z;
      a3 += av * xl.w; a4 += av * xh.x; a5 += av * xh.y;
    }
    y_s[tid * 8 + 0] = a0; y_s[tid * 8 + 1] = a1; y_s[tid * 8 + 2] = a2;
    y_s[tid * 8 + 3] = a3; y_s[tid * 8 + 4] = a4; y_s[tid * 8 + 5] = a5;
  }
  __syncthreads();

  // ---- phase 2: h1[j][lane] for all rows (wave owns 64 j's) ----
  {
    float wg0 = wgc1[lane * Fp + 0], wg1 = wgc1[lane * Fp + 1];
    float wg2 = wgc1[lane * Fp + 2], wg3 = wgc1[lane * Fp + 3];
    float wg4 = wgc1[lane * Fp + 4], wg5 = wgc1[lane * Fp + 5];
    float bg = bgc1[lane];
#pragma unroll 4
    for (int jj = 0; jj < 64; ++jj) {
      int j = wu * 64 + jj;
      float4 yl = *(const float4*)&y_s[j * 8];
      float4 yh = *(const float4*)&y_s[j * 8 + 4];
      float hv = bg + wg0 * yl.x + wg1 * yl.y + wg2 * yl.z + wg3 * yl.w +
                 wg4 * yh.x + wg5 * yh.y;
      h1_s[j * Hh + lane] = fmaxf(hv, 0.f);
    }
  }
  __syncthreads();

  // ---- phase 3: agg z for own 32 rows (wave: rows i0+wu*8 .. +7) ----
  {
    float acc[8];
#pragma unroll
    for (int q = 0; q < 8; ++q) acc[q] = 0.f;
    const float* a2 = A2d + ((long)b * Nn + i0 + wu * 8) * Nn;
#pragma unroll 2
    for (int j = 0; j < Nn; ++j) {
      float hv = h1_s[j * Hh + lane];
#pragma unroll
      for (int q = 0; q < 8; ++q) acc[q] += a2[q * Nn + j] * hv;
    }
#pragma unroll
    for (int q = 0; q < 8; ++q) z_s[wu * 8 + q][lane] = acc[q];
  }

  // ---- phase 4: sf = relu(W2 z + b2)  (wave-private rows) ----
  {
    float s[8];
    float bv = bgc2[lane];
#pragma unroll
    for (int q = 0; q < 8; ++q) s[q] = bv;
    for (int k = 0; k < Hh; ++k) {
      float wk = wgc2T[k * Hh + lane];
#pragma unroll
      for (int q = 0; q < 8; ++q) s[q] += wk * z_s[wu * 8 + q][k];
    }
#pragma unroll
    for (int q = 0; q < 8; ++q) sf_s[wu * 8 + q][lane] = fmaxf(s[q], 0.f);
  }

  // ---- phase 5: GRU (wave-private rows; weights streamed) ----
  {
    float bi_r = bih[lane], bi_z = bih[64 + lane], bi_n = bih[128 + lane];
    float bh_r = bhh[lane], bh_z = bhh[64 + lane], bh_n = bhh[128 + lane];
    float gir[8], giz[8], gin[8], ghr[8], ghz[8], ghn[8];
#pragma unroll
    for (int q = 0; q < 8; ++q) {
      gir[q] = bi_r; giz[q] = bi_z; gin[q] = bi_n;
      ghr[q] = bh_r; ghz[q] = bh_z; ghn[q] = bh_n;
    }
#pragma unroll 2
    for (int kb = 0; kb < 16; ++kb) {
      int k0 = kb * 4;
      float4 wi[4], wh[4];
#pragma unroll
      for (int q = 0; q < 4; ++q) {
        wi[q] = wihP[(k0 + q) * 64 + lane];
        wh[q] = whhP[(k0 + q) * 64 + lane];
      }
#pragma unroll
      for (int q = 0; q < 8; ++q) {
        const float4 s4 = *(const float4*)&sf_s[wu * 8 + q][k0];
        const float4 h4 = *(const float4*)&hp_s[wu * 8 + q][k0];
        gir[q] += s4.x * wi[0].x + s4.y * wi[1].x + s4.z * wi[2].x + s4.w * wi[3].x;
        giz[q] += s4.x * wi[0].y + s4.y * wi[1].y + s4.z * wi[2].y + s4.w * wi[3].y;
        gin[q] += s4.x * wi[0].z + s4.y * wi[1].z + s4.z * wi[2].z + s4.w * wi[3].z;
        ghr[q] += h4.x * wh[0].x + h4.y * wh[1].x + h4.z * wh[2].x + h4.w * wh[3].x;
        ghz[q] += h4.x * wh[0].y + h4.y * wh[1].y + h4.z * wh[2].y + h4.w * wh[3].y;
        ghn[q] += h4.x * wh[0].z + h4.y * wh[1].z + h4.z * wh[2].z + h4.w * wh[3].z;
      }
    }
#pragma unroll
    for (int q = 0; q < 8; ++q) {
      float rg = 1.f / (1.f + expf(-(gir[q] + ghr[q])));
      float zg = 1.f / (1.f + expf(-(giz[q] + ghz[q])));
      float ng = tanhf(gin[q] + rg * ghn[q]);
      float hn = (1.f - zg) * ng + zg * hp_s[wu * 8 + q][lane];
      hstate[((long)b * Nn + i0 + wu * 8 + q) * Hh + lane] = hn;
      z_s[wu * 8 + q][lane] = hn;   // reuse z region as hn (wave-private)
    }
  }
  __syncthreads();

  // ---- phase 6: MLP -> out, xb_out (own 32 rows) ----
#pragma unroll
  for (int c = 0; c < 4; ++c) {
    int idx = tid + c * 256;
    int row = idx >> 5, m = idx & 31;
    float um = bm1[m];
    for (int k = 0; k < Hh; ++k) um += wm1T[k * M1 + m] * z_s[row][k];
    u_s2[row][m] = fmaxf(um, 0.f);
  }
  __syncthreads();
  if (tid < 32 * Fp) {
    int row = tid / Fp, f = tid - row * Fp;
    float pf = bm2[f];
#pragma unroll
    for (int m = 0; m < M1; ++m) pf += wm2T[m * Fp + f] * u_s2[row][m];
    int i = i0 + row;
    outp[(((long)b * PredL + p) * Nn + i) * Fp + f] = pf;
    xb_out[((long)b * Nn + i) * Fp + f] = pf;
  }
}

// ---------------------------------------------------------------------------
extern "C" void kernel_launch(void* const* d_in, const int* in_sizes, int n_in,
                              void* d_out, int out_size, void* d_ws, size_t ws_size,
                              hipStream_t stream) {
  const float* hp     = (const float*)d_in[0];
  const float* hw     = (const float*)d_in[1];
  const float* adj    = (const float*)d_in[2];
  const float* coords = (const float*)d_in[3];
  const float* wgc1   = (const float*)d_in[4];
  const float* bgc1   = (const float*)d_in[5];
  const float* wgc2   = (const float*)d_in[6];
  const float* bgc2   = (const float*)d_in[7];
  const float* wih    = (const float*)d_in[8];
  const float* whh    = (const float*)d_in[9];
  const float* bih    = (const float*)d_in[10];
  const float* bhh    = (const float*)d_in[11];
  const float* wm1    = (const float*)d_in[12];
  const float* bm1    = (const float*)d_in[13];
  const float* wm2    = (const float*)d_in[14];
  const float* bm2    = (const float*)d_in[15];
  float* out = (float*)d_out;

  float* w = (float*)d_ws;
  float2* pk    = (float2*)w; w += Nn * Nn * 2;
  float* d23    = w; w += Bsz * Nn;
  float* e23    = w; w += Bsz * Nn;
  float* hstate = w; w += Bsz * Nn * Hh;
  float* sf_all = w; w += (long)Tt * Bsz * Nn * Hh;
  float* gi_ch  = w; w += (long)TCHUNK * Bsz * Nn * 3 * 64;
  float* xb0    = w; w += Bsz * Nn * Fp;
  float* xb1    = w; w += Bsz * Nn * Fp;
  float* AT     = w; w += Bsz * Nn * Nn;
  float* A2d    = w; w += Bsz * Nn * Nn;
  float* wgc2T  = w; w += Hh * Hh;
  float* wm1T   = w; w += Hh * M1;
  float* wm2T   = w; w += M1 * Fp;
  float4* wihP  = (float4*)w; w += Hh * 64 * 4;
  float4* whhP  = (float4*)w; w += Hh * 64 * 4;

  k_prep<<<Nn + 1, 256, 0, stream>>>(coords, adj, wgc2, wih, whh, wm1, wm2,
                                     pk, wgc2T, wm1T, wm2T, wihP, whhP);
  k_enc<<<Tt * Bsz, 256, 0, stream>>>(pk, hp, hw, wgc1, bgc1, wgc2T, bgc2,
                                      sf_all, d23, e23);
  for (int s = 0; s < Tt / TCHUNK; ++s) {
    int t0 = s * TCHUNK;
    k_gi<<<(TCHUNK * Bsz * Nn) / 64, 256, 0, stream>>>(sf_all, wihP, bih,
                                                       gi_ch, t0);
    k_gru_scan4<<<Bsz * 16, 256, 0, stream>>>(gi_ch, whhP, bhh, hstate,
                                              t0, TCHUNK);
  }
  k_misc<<<Bsz * Nn + Bsz * Nn / 16, 256, 0, stream>>>(
      hw, pk, d23, e23, AT, A2d, hstate, wm1T, bm1, wm2T, bm2, xb0);

  for (int p = 0; p < PredL; ++p) {
    float* xin  = (p & 1) ? xb1 : xb0;
    float* xout = (p & 1) ? xb0 : xb1;
    k_dstep<<<Bsz * 8, 256, 0, stream>>>(
        AT, A2d, xin, hstate, wihP, whhP, wgc2T, wgc1, bgc1, bgc2,
        bih, bhh, wm1T, bm1, wm2T, bm2, out, xout, p);
  }
}

// Round 10
// 870.970 us; speedup vs baseline: 1.3376x; 1.3376x over previous
//
#include <hip/hip_runtime.h>
#include <math.h>

#define Bsz 16
#define Tt 24
#define Nn 256
#define Fp 6
#define Hh 64
#define PredL 12
#define Fw 4
#define M1 32
#define TCHUNK 12
#define DEG2RAD 0.017453292519943295f
#define IDX2(t, b) ((t) * Bsz + (b))

// ---------------------------------------------------------------------------
// P0+PT: blocks 0..255 build packed pk[i][j] = {Ac,As}; block 256 repacks
// weights (wgc2T[k][g], wm1T, wm2T, wihP/whhP float4 {r,z,n,0} per [k][lane]).
// ---------------------------------------------------------------------------
__global__ __launch_bounds__(256) void k_prep(
    const float* __restrict__ coords, const float* __restrict__ adj,
    const float* __restrict__ wgc2, const float* __restrict__ wih,
    const float* __restrict__ whh,  const float* __restrict__ wm1,
    const float* __restrict__ wm2,
    float2* __restrict__ pk,
    float* __restrict__ wgc2T, float* __restrict__ wm1T, float* __restrict__ wm2T,
    float4* __restrict__ wihP, float4* __restrict__ whhP) {
  int tid = threadIdx.x;
  if (blockIdx.x < Nn) {
    int i = blockIdx.x;
    int j = tid;
    float dx = coords[2 * j]     - coords[2 * i];
    float dy = coords[2 * j + 1] - coords[2 * i + 1];
    float ang = atan2f(dy, dx);
    float a = adj[i * Nn + j];
    pk[i * Nn + j] = make_float2(a * cosf(ang), a * sinf(ang));
    return;
  }
  for (int idx = tid; idx < Hh * Hh; idx += 256) {
    int g = idx / Hh, k = idx % Hh;
    wgc2T[k * Hh + g] = wgc2[g * Hh + k];
  }
  for (int idx = tid; idx < M1 * Hh; idx += 256) {
    int m = idx / Hh, k = idx % Hh;
    wm1T[k * M1 + m] = wm1[m * Hh + k];
  }
  for (int idx = tid; idx < Fp * M1; idx += 256) {
    int f = idx / M1, m = idx % M1;
    wm2T[m * Fp + f] = wm2[f * M1 + m];
  }
  for (int idx = tid; idx < Hh * 64; idx += 256) {
    int k = idx >> 6, lane = idx & 63;
    wihP[idx] = make_float4(wih[(0 * 64 + lane) * Hh + k],
                            wih[(1 * 64 + lane) * Hh + k],
                            wih[(2 * 64 + lane) * Hh + k], 0.f);
    whhP[idx] = make_float4(whh[(0 * 64 + lane) * Hh + k],
                            whh[(1 * 64 + lane) * Hh + k],
                            whh[(2 * 64 + lane) * Hh + k], 0.f);
  }
}

// ---------------------------------------------------------------------------
// E: fused encoder: deg + gconv1 + gconv2 + W2 -> sf_all. One block per (t,b).
// (measured 153us, round 9)
// ---------------------------------------------------------------------------
__global__ __launch_bounds__(256) void k_enc(
    const float2* __restrict__ pk, const float* __restrict__ hp,
    const float* __restrict__ hw,
    const float* __restrict__ wgc1, const float* __restrict__ bgc1,
    const float* __restrict__ wgc2T, const float* __restrict__ bgc2,
    float* __restrict__ sf_all,
    float* __restrict__ d23, float* __restrict__ e23) {
  __shared__ float d_lds[Nn];
  __shared__ float e_lds[Nn];
  __shared__ __align__(16) float u_s[Nn * 8];     // 8KB
  __shared__ __align__(16) float h1_s[Nn * 68];   // 69.6KB
  int tb = blockIdx.x, t = tb / Bsz, b = tb % Bsz;
  int tid = threadIdx.x;
  int i = tid;
  float spd = hw[(b * Tt + t) * Fw + 2];
  float rad = hw[(b * Tt + t) * Fw + 1] * DEG2RAD;
  float scr = spd * cosf(rad), ssr = spd * sinf(rad);

  // ---- pass 0: degrees (from column i of pk) ----
  {
    float rs = 0.f, cs = 0.f;
#pragma unroll 4
    for (int j = 0; j < Nn; ++j) {
      float2 pv = pk[j * Nn + i];
      float v = pv.x * scr + pv.y * ssr;   // V(j,i)
      cs += fmaxf(v, 0.f);
      rs += fmaxf(-v, 0.f);
    }
    float2 pd = pk[i * Nn + i];
    float vii = pd.x * scr + pd.y * ssr;
    rs += vii;  // diag fix
    float di = 1.f / (sqrtf(rs + 1.f) + 1e-6f);
    float ei = 1.f / (sqrtf(cs + 1.f) + 1e-6f);
    d_lds[i] = di; e_lds[i] = ei;
    if (t == Tt - 1) { d23[b * Nn + i] = di; e23[b * Nn + i] = ei; }
  }
  __syncthreads();

  // ---- stage u = d_j * x ----
  {
    const float* xsrc = hp + (long)(b * Tt + t) * Nn * Fp;
    for (int idx = tid; idx < Nn * Fp; idx += 256) {
      int j = idx / Fp, f = idx - j * Fp;
      u_s[j * 8 + f] = d_lds[j] * xsrc[idx];
    }
    u_s[tid * 8 + 6] = 0.f;
    u_s[tid * 8 + 7] = 0.f;
  }
  __syncthreads();

  // ---- pass 1: gconv1 for row i; e-scaled h1 row -> LDS ----
  {
    float a0 = 0.f, a1 = 0.f, a2 = 0.f, a3 = 0.f, a4 = 0.f, a5 = 0.f;
#pragma unroll 2
    for (int j = 0; j < Nn; ++j) {
      float2 pv = pk[j * Nn + i];
      float v = pv.x * scr + pv.y * ssr;
      float w = fmaxf(-v, 0.f);            // wout[i][j], wrong on diag
      float4 ul = *(const float4*)&u_s[j * 8];
      float4 uh = *(const float4*)&u_s[j * 8 + 4];
      a0 += w * ul.x; a1 += w * ul.y; a2 += w * ul.z;
      a3 += w * ul.w; a4 += w * uh.x; a5 += w * uh.y;
    }
    float2 pd = pk[i * Nn + i];
    float vii = pd.x * scr + pd.y * ssr;
    float di = d_lds[i], ei = e_lds[i];
    float c1 = vii + 1.f;  // diag fix + identity
    float y0 = di * (a0 + c1 * u_s[i * 8 + 0]);
    float y1 = di * (a1 + c1 * u_s[i * 8 + 1]);
    float y2 = di * (a2 + c1 * u_s[i * 8 + 2]);
    float y3 = di * (a3 + c1 * u_s[i * 8 + 3]);
    float y4 = di * (a4 + c1 * u_s[i * 8 + 4]);
    float y5 = di * (a5 + c1 * u_s[i * 8 + 5]);
#pragma unroll
    for (int g4 = 0; g4 < 16; ++g4) {
      float4 hv;
#pragma unroll
      for (int q = 0; q < 4; ++q) {
        int g = g4 * 4 + q;
        float v2 = bgc1[g] + wgc1[g * Fp + 0] * y0 + wgc1[g * Fp + 1] * y1 +
                   wgc1[g * Fp + 2] * y2 + wgc1[g * Fp + 3] * y3 +
                   wgc1[g * Fp + 4] * y4 + wgc1[g * Fp + 5] * y5;
        ((float*)&hv)[q] = fmaxf(v2, 0.f) * ei;
      }
      *(float4*)&h1_s[i * 68 + g4 * 4] = hv;
    }
  }
  __syncthreads();

  // ---- pass 2: z[i][g] = e_i * sum_j (win+I)[i][j] h1e[j] ----
  float z[64];
#pragma unroll
  for (int k = 0; k < 64; ++k) z[k] = 0.f;
#pragma unroll 2
  for (int j = 0; j < Nn; ++j) {
    float2 pv = pk[j * Nn + i];
    float v = pv.x * scr + pv.y * ssr;     // V(j,i)
    float wf = fmaxf(v, 0.f) + ((j == i) ? 1.f : 0.f);
#pragma unroll
    for (int g4 = 0; g4 < 16; ++g4) {
      float4 h4 = *(const float4*)&h1_s[j * 68 + g4 * 4];
      z[g4 * 4 + 0] += wf * h4.x;
      z[g4 * 4 + 1] += wf * h4.y;
      z[g4 * 4 + 2] += wf * h4.z;
      z[g4 * 4 + 3] += wf * h4.w;
    }
  }
  {
    float ei = e_lds[i];
#pragma unroll
    for (int k = 0; k < 64; ++k) z[k] *= ei;
  }
  __syncthreads();   // h1_s free; reuse for sf staging

  // ---- W2 + relu -> staged in h1_s, then coalesced store ----
#pragma unroll
  for (int c = 0; c < 4; ++c) {
    float s[16];
#pragma unroll
    for (int q = 0; q < 16; ++q) s[q] = bgc2[c * 16 + q];
#pragma unroll
    for (int k = 0; k < 64; ++k) {
      float zk = z[k];
#pragma unroll
      for (int q = 0; q < 16; ++q) s[q] += wgc2T[k * Hh + c * 16 + q] * zk;
    }
#pragma unroll
    for (int q4 = 0; q4 < 4; ++q4) {
      float4 sv = make_float4(fmaxf(s[q4 * 4 + 0], 0.f), fmaxf(s[q4 * 4 + 1], 0.f),
                              fmaxf(s[q4 * 4 + 2], 0.f), fmaxf(s[q4 * 4 + 3], 0.f));
      *(float4*)&h1_s[i * 68 + c * 16 + q4 * 4] = sv;
    }
  }
  __syncthreads();
  long base = (long)IDX2(t, b) * Nn * Hh;
  for (int idx = tid; idx < Nn * 16; idx += 256) {
    int j = idx >> 4, g4 = idx & 15;
    *(float4*)&sf_all[base + j * Hh + g4 * 4] = *(const float4*)&h1_s[j * 68 + g4 * 4];
  }
}

// ---------------------------------------------------------------------------
// GI: gi = sf @ W_ih^T + b_ih for TCHUNK timesteps (16 rows/wave, VALU-bound)
// ---------------------------------------------------------------------------
__global__ __launch_bounds__(256) void k_gi(
    const float* __restrict__ sf_all, const float4* __restrict__ wihP,
    const float* __restrict__ bih, float* __restrict__ gi, int t0) {
  __shared__ float sf_c[4][16][64];
  int tid = threadIdx.x, w = tid >> 6, lane = tid & 63;
  int rowc0 = blockIdx.x * 64 + w * 16;
  long rowg0 = (long)t0 * (Bsz * Nn) + rowc0;
#pragma unroll
  for (int rr = 0; rr < 16; ++rr)
    sf_c[w][rr][lane] = sf_all[(rowg0 + rr) * Hh + lane];
  float bi_r = bih[lane], bi_z = bih[64 + lane], bi_n = bih[128 + lane];
  float ar[16], az[16], an[16];
#pragma unroll
  for (int rr = 0; rr < 16; ++rr) { ar[rr] = bi_r; az[rr] = bi_z; an[rr] = bi_n; }
#pragma unroll 2
  for (int kb = 0; kb < 16; ++kb) {
    int k0 = kb * 4;
    float4 wi0 = wihP[(k0 + 0) * 64 + lane];
    float4 wi1 = wihP[(k0 + 1) * 64 + lane];
    float4 wi2 = wihP[(k0 + 2) * 64 + lane];
    float4 wi3 = wihP[(k0 + 3) * 64 + lane];
#pragma unroll
    for (int rr = 0; rr < 16; ++rr) {
      const float4 s4 = *(const float4*)&sf_c[w][rr][k0];
      ar[rr] += s4.x * wi0.x + s4.y * wi1.x + s4.z * wi2.x + s4.w * wi3.x;
      az[rr] += s4.x * wi0.y + s4.y * wi1.y + s4.z * wi2.y + s4.w * wi3.y;
      an[rr] += s4.x * wi0.z + s4.y * wi1.z + s4.z * wi2.z + s4.w * wi3.z;
    }
  }
#pragma unroll
  for (int rr = 0; rr < 16; ++rr) {
    long rowc = rowc0 + rr;
    gi[(rowc * 3 + 0) * 64 + lane] = ar[rr];
    gi[(rowc * 3 + 1) * 64 + lane] = az[rr];
    gi[(rowc * 3 + 2) * 64 + lane] = an[rr];
  }
}

// ---------------------------------------------------------------------------
// GRU scan over one chunk (gh only; whh streamed; h broadcast via LDS rows)
// ---------------------------------------------------------------------------
__global__ __launch_bounds__(256) void k_gru_scan4(
    const float* __restrict__ gi, const float4* __restrict__ whhP,
    const float* __restrict__ bhh, float* __restrict__ hstate,
    int t0, int nt) {
  __shared__ float h_s[16][64];
  int b = blockIdx.x >> 4;
  int i0 = (blockIdx.x & 15) * 16;
  int tid = threadIdx.x, w = tid >> 6, lane = tid & 63;
  float bh_r = bhh[lane], bh_z = bhh[64 + lane], bh_n = bhh[128 + lane];
  float h_reg[4];
#pragma unroll
  for (int rr = 0; rr < 4; ++rr) {
    float hv = (t0 == 0) ? 0.f
                         : hstate[((long)b * Nn + i0 + w * 4 + rr) * Hh + lane];
    h_reg[rr] = hv;
    h_s[w * 4 + rr][lane] = hv;
  }
  for (int tl = 0; tl < nt; ++tl) {
    long rbase = ((long)tl * Bsz + b) * Nn + i0 + w * 4;
    float gr[4], gz[4], gn[4], hr[4], hz[4], hn[4];
#pragma unroll
    for (int rr = 0; rr < 4; ++rr) {
      gr[rr] = gi[((rbase + rr) * 3 + 0) * 64 + lane];
      gz[rr] = gi[((rbase + rr) * 3 + 1) * 64 + lane];
      gn[rr] = gi[((rbase + rr) * 3 + 2) * 64 + lane];
      hr[rr] = bh_r; hz[rr] = bh_z; hn[rr] = bh_n;
    }
#pragma unroll 4
    for (int kb = 0; kb < 16; ++kb) {
      int k0 = kb * 4;
      float4 wh0 = whhP[(k0 + 0) * 64 + lane];
      float4 wh1 = whhP[(k0 + 1) * 64 + lane];
      float4 wh2 = whhP[(k0 + 2) * 64 + lane];
      float4 wh3 = whhP[(k0 + 3) * 64 + lane];
#pragma unroll
      for (int rr = 0; rr < 4; ++rr) {
        const float4 h4 = *(const float4*)&h_s[w * 4 + rr][k0];
        hr[rr] += h4.x * wh0.x + h4.y * wh1.x + h4.z * wh2.x + h4.w * wh3.x;
        hz[rr] += h4.x * wh0.y + h4.y * wh1.y + h4.z * wh2.y + h4.w * wh3.y;
        hn[rr] += h4.x * wh0.z + h4.y * wh1.z + h4.z * wh2.z + h4.w * wh3.z;
      }
    }
#pragma unroll
    for (int rr = 0; rr < 4; ++rr) {
      float rg = 1.f / (1.f + expf(-(gr[rr] + hr[rr])));
      float zg = 1.f / (1.f + expf(-(gz[rr] + hz[rr])));
      float ng = tanhf(gn[rr] + rg * hn[rr]);
      float hv = (1.f - zg) * ng + zg * h_reg[rr];
      h_reg[rr] = hv;
      h_s[w * 4 + rr][lane] = hv;
    }
  }
#pragma unroll
  for (int rr = 0; rr < 4; ++rr)
    hstate[((long)b * Nn + i0 + w * 4 + rr) * Hh + lane] = h_reg[rr];
}

// ---------------------------------------------------------------------------
// MISC: blocks < Bsz*Nn: decoder adjacencies AT[i][j]=A1[j][i], A2d[i][j].
//       blocks >= Bsz*Nn: dec0 (x0 = mlp(h)).
// ---------------------------------------------------------------------------
__global__ __launch_bounds__(256) void k_misc(
    const float* __restrict__ hw, const float2* __restrict__ pk,
    const float* __restrict__ d23, const float* __restrict__ e23,
    float* __restrict__ AT, float* __restrict__ A2d,
    const float* __restrict__ hstate,
    const float* __restrict__ wm1T, const float* __restrict__ bm1,
    const float* __restrict__ wm2T, const float* __restrict__ bm2,
    float* __restrict__ xnext) {
  __shared__ float h_lds[16][Hh];
  __shared__ float u_lds[16][M1];
  int tid = threadIdx.x;
  if (blockIdx.x < Bsz * Nn) {
    int b = blockIdx.x >> 8;
    int i = blockIdx.x & 255;
    int j = tid;
    float spd = hw[(b * Tt + (Tt - 1)) * Fw + 2];
    float rad = hw[(b * Tt + (Tt - 1)) * Fw + 1] * DEG2RAD;
    float cr = cosf(rad), sr = sinf(rad);
    const float* drow = d23 + b * Nn;
    const float* erow = e23 + b * Nn;
    float2 pv = pk[i * Nn + j];
    float val = spd * (pv.x * cr + pv.y * sr);
    float dlt = (j == i) ? 1.f : 0.f;
    float wtji = (j == i) ? fmaxf(val, 0.f) : fmaxf(-val, 0.f);
    AT[((long)b * Nn + i) * Nn + j]  = drow[j] * (wtji + dlt) * drow[i];
    A2d[((long)b * Nn + i) * Nn + j] = erow[i] * (wtji + dlt) * erow[j];
    return;
  }
  int r0 = (blockIdx.x - Bsz * Nn) * 16;
#pragma unroll
  for (int c = 0; c < 4; ++c) {
    int idx = tid + c * 256;
    h_lds[idx >> 6][idx & 63] = hstate[(long)r0 * Hh + idx];
  }
  __syncthreads();
#pragma unroll
  for (int rep = 0; rep < 2; ++rep) {
    int idx = tid + rep * 256;
    int row = idx >> 5, m = idx & 31;
    float um = bm1[m];
    for (int k = 0; k < Hh; ++k) um += wm1T[k * M1 + m] * h_lds[row][k];
    u_lds[row][m] = fmaxf(um, 0.f);
  }
  __syncthreads();
  if (tid < 16 * Fp) {
    int row = tid / Fp, f = tid % Fp;
    float pf = bm2[f];
#pragma unroll
    for (int m = 0; m < M1; ++m) pf += wm2T[m * Fp + f] * u_lds[row][m];
    xnext[(r0 + row) * Fp + f] = pf;
  }
}

// ---------------------------------------------------------------------------
// Ddec fused v2: ONE kernel per step, 256 blocks (16 b x 16 groups of 16 rows).
// Full h1 in LDS (pad-65, conflict-free writes+reads); A2 rows staged as wvT
// (coalesced); agg/W2/GRU/MLP wave-private (dstep_B's measured pattern).
// 107KB LDS -> 1 block/CU, all 256 CUs busy.
// ---------------------------------------------------------------------------
__global__ __launch_bounds__(256) void k_dstep(
    const float* __restrict__ AT, const float* __restrict__ A2d,
    const float* __restrict__ xb_in, float* __restrict__ hstate,
    const float4* __restrict__ wihP, const float4* __restrict__ whhP,
    const float* __restrict__ wgc2T, const float* __restrict__ wgc1,
    const float* __restrict__ bgc1, const float* __restrict__ bgc2,
    const float* __restrict__ bih, const float* __restrict__ bhh,
    const float* __restrict__ wm1T, const float* __restrict__ bm1,
    const float* __restrict__ wm2T, const float* __restrict__ bm2,
    float* __restrict__ outp, float* __restrict__ xb_out, int p) {
  __shared__ __align__(16) float x_s[Nn * 8];     // 8KB
  __shared__ float h1_s[Nn * 65];                 // 65KB [j*65+g]
  __shared__ __align__(16) float wvT[Nn * 20];    // 20KB
  __shared__ float z_s[16][Hh];                   // 4KB (wave-private rows)
  __shared__ float sf_s[16][Hh];                  // 4KB
  __shared__ float hp_s[16][Hh];                  // 4KB
  __shared__ float hn_s[16][Hh];                  // 4KB
  __shared__ float u_s2[16][M1];                  // 2KB

  int b = blockIdx.x >> 4;
  int i0 = (blockIdx.x & 15) * 16;
  int tid = threadIdx.x, w = tid >> 6, lane = tid & 63;

  // ---- stage: x (padded), wvT (own A2 rows, coalesced), hprev (own rows) ----
  for (int idx = tid; idx < Nn * Fp; idx += 256) {
    int j = idx / Fp, f = idx - j * Fp;
    x_s[j * 8 + f] = xb_in[(long)b * Nn * Fp + idx];
  }
  x_s[tid * 8 + 6] = 0.f;
  x_s[tid * 8 + 7] = 0.f;
#pragma unroll
  for (int r = 0; r < 16; ++r)
    wvT[tid * 20 + r] = A2d[((long)b * Nn + i0 + r) * Nn + tid];
  float hp_reg[4];
#pragma unroll
  for (int rr = 0; rr < 4; ++rr) {
    hp_reg[rr] = hstate[((long)b * Nn + i0 + w * 4 + rr) * Hh + lane];
    hp_s[w * 4 + rr][lane] = hp_reg[rr];
  }
  __syncthreads();

  // ---- phase 1: y[j=tid] = sum_m AT[m][j] x[m]; then h1 row -> LDS ----
  {
    float a0 = 0.f, a1 = 0.f, a2 = 0.f, a3 = 0.f, a4 = 0.f, a5 = 0.f;
    const float* atb = AT + (long)b * Nn * Nn;
#pragma unroll 8
    for (int m = 0; m < Nn; ++m) {
      float av = atb[m * Nn + tid];
      float4 xl = *(const float4*)&x_s[m * 8];
      float4 xh = *(const float4*)&x_s[m * 8 + 4];
      a0 += av * xl.x; a1 += av * xl.y; a2 += av * xl.z;
      a3 += av * xl.w; a4 += av * xh.x; a5 += av * xh.y;
    }
    // h1[tid][g] for all g (pad-65 layout: writes bank = (tid+g)%32, free)
#pragma unroll 8
    for (int g = 0; g < Hh; ++g) {
      float hv = bgc1[g] + wgc1[g * Fp + 0] * a0 + wgc1[g * Fp + 1] * a1 +
                 wgc1[g * Fp + 2] * a2 + wgc1[g * Fp + 3] * a3 +
                 wgc1[g * Fp + 4] * a4 + wgc1[g * Fp + 5] * a5;
      h1_s[tid * 65 + g] = fmaxf(hv, 0.f);
    }
  }
  __syncthreads();

  // ---- phase 3: agg z for own rows (wave w: rows w*4..+3; lane = g) ----
  {
    float acc[4] = {0.f, 0.f, 0.f, 0.f};
#pragma unroll 4
    for (int j = 0; j < Nn; ++j) {
      float hv = h1_s[j * 65 + lane];
      float4 wv = *(const float4*)&wvT[j * 20 + w * 4];
      acc[0] += wv.x * hv; acc[1] += wv.y * hv;
      acc[2] += wv.z * hv; acc[3] += wv.w * hv;
    }
#pragma unroll
    for (int rr = 0; rr < 4; ++rr) z_s[w * 4 + rr][lane] = acc[rr];
  }

  // ---- phase 4: sf = relu(W2 z + b2) (wave-private rows) ----
  {
    float a0 = bgc2[lane], a1 = a0, a2 = a0, a3 = a0;
    for (int k = 0; k < Hh; ++k) {
      float wk = wgc2T[k * Hh + lane];
      a0 += wk * z_s[w * 4 + 0][k];
      a1 += wk * z_s[w * 4 + 1][k];
      a2 += wk * z_s[w * 4 + 2][k];
      a3 += wk * z_s[w * 4 + 3][k];
    }
    sf_s[w * 4 + 0][lane] = fmaxf(a0, 0.f);
    sf_s[w * 4 + 1][lane] = fmaxf(a1, 0.f);
    sf_s[w * 4 + 2][lane] = fmaxf(a2, 0.f);
    sf_s[w * 4 + 3][lane] = fmaxf(a3, 0.f);
  }

  // ---- phase 5: GRU (wave-private rows; weights streamed from L2) ----
  {
    float bi_r = bih[lane], bi_z = bih[64 + lane], bi_n = bih[128 + lane];
    float bh_r = bhh[lane], bh_z = bhh[64 + lane], bh_n = bhh[128 + lane];
    float gir[4], giz[4], gin[4], ghr[4], ghz[4], ghn[4];
#pragma unroll
    for (int rr = 0; rr < 4; ++rr) {
      gir[rr] = bi_r; giz[rr] = bi_z; gin[rr] = bi_n;
      ghr[rr] = bh_r; ghz[rr] = bh_z; ghn[rr] = bh_n;
    }
#pragma unroll 4
    for (int kb = 0; kb < 16; ++kb) {
      int k0 = kb * 4;
      float4 wi[4], wh[4];
#pragma unroll
      for (int q = 0; q < 4; ++q) {
        wi[q] = wihP[(k0 + q) * 64 + lane];
        wh[q] = whhP[(k0 + q) * 64 + lane];
      }
#pragma unroll
      for (int rr = 0; rr < 4; ++rr) {
        const float4 s4 = *(const float4*)&sf_s[w * 4 + rr][k0];
        const float4 h4 = *(const float4*)&hp_s[w * 4 + rr][k0];
        gir[rr] += s4.x * wi[0].x + s4.y * wi[1].x + s4.z * wi[2].x + s4.w * wi[3].x;
        giz[rr] += s4.x * wi[0].y + s4.y * wi[1].y + s4.z * wi[2].y + s4.w * wi[3].y;
        gin[rr] += s4.x * wi[0].z + s4.y * wi[1].z + s4.z * wi[2].z + s4.w * wi[3].z;
        ghr[rr] += h4.x * wh[0].x + h4.y * wh[1].x + h4.z * wh[2].x + h4.w * wh[3].x;
        ghz[rr] += h4.x * wh[0].y + h4.y * wh[1].y + h4.z * wh[2].y + h4.w * wh[3].y;
        ghn[rr] += h4.x * wh[0].z + h4.y * wh[1].z + h4.z * wh[2].z + h4.w * wh[3].z;
      }
    }
#pragma unroll
    for (int rr = 0; rr < 4; ++rr) {
      float rg = 1.f / (1.f + expf(-(gir[rr] + ghr[rr])));
      float zg = 1.f / (1.f + expf(-(giz[rr] + ghz[rr])));
      float ng = tanhf(gin[rr] + rg * ghn[rr]);
      float hn = (1.f - zg) * ng + zg * hp_reg[rr];
      hstate[((long)b * Nn + i0 + w * 4 + rr) * Hh + lane] = hn;
      hn_s[w * 4 + rr][lane] = hn;
    }
  }
  __syncthreads();

  // ---- phase 6: MLP -> out, xb_out (own 16 rows) ----
#pragma unroll
  for (int rep = 0; rep < 2; ++rep) {
    int idx = tid + rep * 256;
    int row = idx >> 5, m = idx & 31;
    float um = bm1[m];
    for (int k = 0; k < Hh; ++k) um += wm1T[k * M1 + m] * hn_s[row][k];
    u_s2[row][m] = fmaxf(um, 0.f);
  }
  __syncthreads();
  if (tid < 16 * Fp) {
    int row = tid / Fp, f = tid - row * Fp;
    float pf = bm2[f];
#pragma unroll
    for (int m = 0; m < M1; ++m) pf += wm2T[m * Fp + f] * u_s2[row][m];
    int i = i0 + row;
    outp[(((long)b * PredL + p) * Nn + i) * Fp + f] = pf;
    xb_out[((long)b * Nn + i) * Fp + f] = pf;
  }
}

// ---------------------------------------------------------------------------
extern "C" void kernel_launch(void* const* d_in, const int* in_sizes, int n_in,
                              void* d_out, int out_size, void* d_ws, size_t ws_size,
                              hipStream_t stream) {
  const float* hp     = (const float*)d_in[0];
  const float* hw     = (const float*)d_in[1];
  const float* adj    = (const float*)d_in[2];
  const float* coords = (const float*)d_in[3];
  const float* wgc1   = (const float*)d_in[4];
  const float* bgc1   = (const float*)d_in[5];
  const float* wgc2   = (const float*)d_in[6];
  const float* bgc2   = (const float*)d_in[7];
  const float* wih    = (const float*)d_in[8];
  const float* whh    = (const float*)d_in[9];
  const float* bih    = (const float*)d_in[10];
  const float* bhh    = (const float*)d_in[11];
  const float* wm1    = (const float*)d_in[12];
  const float* bm1    = (const float*)d_in[13];
  const float* wm2    = (const float*)d_in[14];
  const float* bm2    = (const float*)d_in[15];
  float* out = (float*)d_out;

  float* w = (float*)d_ws;
  float2* pk    = (float2*)w; w += Nn * Nn * 2;
  float* d23    = w; w += Bsz * Nn;
  float* e23    = w; w += Bsz * Nn;
  float* hstate = w; w += Bsz * Nn * Hh;
  float* sf_all = w; w += (long)Tt * Bsz * Nn * Hh;
  float* gi_ch  = w; w += (long)TCHUNK * Bsz * Nn * 3 * 64;
  float* xb0    = w; w += Bsz * Nn * Fp;
  float* xb1    = w; w += Bsz * Nn * Fp;
  float* AT     = w; w += Bsz * Nn * Nn;
  float* A2d    = w; w += Bsz * Nn * Nn;
  float* wgc2T  = w; w += Hh * Hh;
  float* wm1T   = w; w += Hh * M1;
  float* wm2T   = w; w += M1 * Fp;
  float4* wihP  = (float4*)w; w += Hh * 64 * 4;
  float4* whhP  = (float4*)w; w += Hh * 64 * 4;

  k_prep<<<Nn + 1, 256, 0, stream>>>(coords, adj, wgc2, wih, whh, wm1, wm2,
                                     pk, wgc2T, wm1T, wm2T, wihP, whhP);
  k_enc<<<Tt * Bsz, 256, 0, stream>>>(pk, hp, hw, wgc1, bgc1, wgc2T, bgc2,
                                      sf_all, d23, e23);
  for (int s = 0; s < Tt / TCHUNK; ++s) {
    int t0 = s * TCHUNK;
    k_gi<<<(TCHUNK * Bsz * Nn) / 64, 256, 0, stream>>>(sf_all, wihP, bih,
                                                       gi_ch, t0);
    k_gru_scan4<<<Bsz * 16, 256, 0, stream>>>(gi_ch, whhP, bhh, hstate,
                                              t0, TCHUNK);
  }
  k_misc<<<Bsz * Nn + Bsz * Nn / 16, 256, 0, stream>>>(
      hw, pk, d23, e23, AT, A2d, hstate, wm1T, bm1, wm2T, bm2, xb0);

  for (int p = 0; p < PredL; ++p) {
    float* xin  = (p & 1) ? xb1 : xb0;
    float* xout = (p & 1) ? xb0 : xb1;
    k_dstep<<<Bsz * 16, 256, 0, stream>>>(
        AT, A2d, xin, hstate, wihP, whhP, wgc2T, wgc1, bgc1, bgc2,
        bih, bhh, wm1T, bm1, wm2T, bm2, out, xout, p);
  }
}

// Round 11
// 817.774 us; speedup vs baseline: 1.4246x; 1.0650x over previous
//
#include <hip/hip_runtime.h>
#include <math.h>

#define Bsz 16
#define Tt 24
#define Nn 256
#define Fp 6
#define Hh 64
#define PredL 12
#define Fw 4
#define M1 32
#define TCHUNK 12
#define DEG2RAD 0.017453292519943295f
#define IDX2(t, b) ((t) * Bsz + (b))

// ---------------------------------------------------------------------------
// P0+PT: blocks 0..255 build packed pk[i][j] = {Ac,As}; block 256 repacks
// weights (wgc2T[k][g], wm1T, wm2T, wihP/whhP float4 {r,z,n,0} per [k][lane]).
// ---------------------------------------------------------------------------
__global__ __launch_bounds__(256) void k_prep(
    const float* __restrict__ coords, const float* __restrict__ adj,
    const float* __restrict__ wgc2, const float* __restrict__ wih,
    const float* __restrict__ whh,  const float* __restrict__ wm1,
    const float* __restrict__ wm2,
    float2* __restrict__ pk,
    float* __restrict__ wgc2T, float* __restrict__ wm1T, float* __restrict__ wm2T,
    float4* __restrict__ wihP, float4* __restrict__ whhP) {
  int tid = threadIdx.x;
  if (blockIdx.x < Nn) {
    int i = blockIdx.x;
    int j = tid;
    float dx = coords[2 * j]     - coords[2 * i];
    float dy = coords[2 * j + 1] - coords[2 * i + 1];
    float ang = atan2f(dy, dx);
    float a = adj[i * Nn + j];
    pk[i * Nn + j] = make_float2(a * cosf(ang), a * sinf(ang));
    return;
  }
  for (int idx = tid; idx < Hh * Hh; idx += 256) {
    int g = idx / Hh, k = idx % Hh;
    wgc2T[k * Hh + g] = wgc2[g * Hh + k];
  }
  for (int idx = tid; idx < M1 * Hh; idx += 256) {
    int m = idx / Hh, k = idx % Hh;
    wm1T[k * M1 + m] = wm1[m * Hh + k];
  }
  for (int idx = tid; idx < Fp * M1; idx += 256) {
    int f = idx / M1, m = idx % M1;
    wm2T[m * Fp + f] = wm2[f * M1 + m];
  }
  for (int idx = tid; idx < Hh * 64; idx += 256) {
    int k = idx >> 6, lane = idx & 63;
    wihP[idx] = make_float4(wih[(0 * 64 + lane) * Hh + k],
                            wih[(1 * 64 + lane) * Hh + k],
                            wih[(2 * 64 + lane) * Hh + k], 0.f);
    whhP[idx] = make_float4(whh[(0 * 64 + lane) * Hh + k],
                            whh[(1 * 64 + lane) * Hh + k],
                            whh[(2 * 64 + lane) * Hh + k], 0.f);
  }
}

// ---------------------------------------------------------------------------
// E: fused encoder (round-7 verified 2-rows-per-thread form): deg + gconv1 +
// gconv2 + W2 -> sf_all. One block per (t,b), 128 threads, rows (tid, tid+128).
// Pass-2 reads each h1e row ONCE per j and feeds 128 FMA (2 rows x 64 g).
// ---------------------------------------------------------------------------
__global__ __launch_bounds__(128, 1) void k_enc(
    const float2* __restrict__ pk, const float* __restrict__ hp,
    const float* __restrict__ hw,
    const float* __restrict__ wgc1, const float* __restrict__ bgc1,
    const float* __restrict__ wgc2T, const float* __restrict__ bgc2,
    float* __restrict__ sf_all,
    float* __restrict__ d23, float* __restrict__ e23) {
  __shared__ float d_lds[Nn];
  __shared__ float e_lds[Nn];
  __shared__ __align__(16) float u_s[Nn * 8];     // 8KB
  __shared__ __align__(16) float h1_s[Nn * 68];   // 69.6KB
  int tb = blockIdx.x, t = tb / Bsz, b = tb % Bsz;
  int tid = threadIdx.x;
  int ia = tid, ib = tid + 128;
  float spd = hw[(b * Tt + t) * Fw + 2];
  float rad = hw[(b * Tt + t) * Fw + 1] * DEG2RAD;
  float scr = spd * cosf(rad), ssr = spd * sinf(rad);

  // ---- pass 0: degrees (from columns ia, ib of pk) ----
  {
    float rs_a = 0.f, cs_a = 0.f, rs_b = 0.f, cs_b = 0.f;
#pragma unroll 4
    for (int j = 0; j < Nn; ++j) {
      float2 pa = pk[j * Nn + ia];
      float2 pb = pk[j * Nn + ib];
      float va = pa.x * scr + pa.y * ssr;   // V(j,ia)
      float vb = pb.x * scr + pb.y * ssr;
      float vap = fmaxf(va, 0.f), vbp = fmaxf(vb, 0.f);
      cs_a += vap;
      cs_b += vbp;
      rs_a += (j == ia) ? vap : fmaxf(-va, 0.f);
      rs_b += (j == ib) ? vbp : fmaxf(-vb, 0.f);
    }
    d_lds[ia] = 1.f / (sqrtf(rs_a + 1.f) + 1e-6f);
    d_lds[ib] = 1.f / (sqrtf(rs_b + 1.f) + 1e-6f);
    e_lds[ia] = 1.f / (sqrtf(cs_a + 1.f) + 1e-6f);
    e_lds[ib] = 1.f / (sqrtf(cs_b + 1.f) + 1e-6f);
    if (t == Tt - 1) {
      d23[b * Nn + ia] = d_lds[ia]; d23[b * Nn + ib] = d_lds[ib];
      e23[b * Nn + ia] = e_lds[ia]; e23[b * Nn + ib] = e_lds[ib];
    }
  }
  __syncthreads();

  // ---- stage u = d_j * x ----
  {
    const float* xsrc = hp + (long)(b * Tt + t) * Nn * Fp;
    for (int idx = tid; idx < Nn * Fp; idx += 128) {
      int j = idx / Fp, f = idx - j * Fp;
      u_s[j * 8 + f] = d_lds[j] * xsrc[idx];
    }
    u_s[ia * 8 + 6] = 0.f; u_s[ia * 8 + 7] = 0.f;
    u_s[ib * 8 + 6] = 0.f; u_s[ib * 8 + 7] = 0.f;
  }
  __syncthreads();

  float da = d_lds[ia], db = d_lds[ib];
  float ea = e_lds[ia], eb = e_lds[ib];

  // ---- pass 1: gconv1 for 2 rows ----
  float ya[Fp], yb[Fp];
  {
    float aa[Fp] = {0, 0, 0, 0, 0, 0}, ab[Fp] = {0, 0, 0, 0, 0, 0};
#pragma unroll 2
    for (int j = 0; j < Nn; ++j) {
      float2 pa = pk[j * Nn + ia];
      float2 pb = pk[j * Nn + ib];
      float va = pa.x * scr + pa.y * ssr;
      float vb = pb.x * scr + pb.y * ssr;
      float wa = (j == ia) ? fmaxf(va, 0.f) : fmaxf(-va, 0.f);
      float wb = (j == ib) ? fmaxf(vb, 0.f) : fmaxf(-vb, 0.f);
      float4 ul = *(const float4*)&u_s[j * 8];
      float4 uh = *(const float4*)&u_s[j * 8 + 4];
      aa[0] += wa * ul.x; aa[1] += wa * ul.y; aa[2] += wa * ul.z;
      aa[3] += wa * ul.w; aa[4] += wa * uh.x; aa[5] += wa * uh.y;
      ab[0] += wb * ul.x; ab[1] += wb * ul.y; ab[2] += wb * ul.z;
      ab[3] += wb * ul.w; ab[4] += wb * uh.x; ab[5] += wb * uh.y;
    }
#pragma unroll
    for (int f = 0; f < Fp; ++f) {
      ya[f] = da * (aa[f] + u_s[ia * 8 + f]);
      yb[f] = db * (ab[f] + u_s[ib * 8 + f]);
    }
  }

  // ---- h1 rows (e-scaled) into LDS ----
#pragma unroll
  for (int g4 = 0; g4 < 16; ++g4) {
    float4 hva, hvb;
#pragma unroll
    for (int q = 0; q < 4; ++q) {
      int g = g4 * 4 + q;
      float va = bgc1[g], vb = va;
#pragma unroll
      for (int f = 0; f < Fp; ++f) {
        float wg = wgc1[g * Fp + f];
        va += wg * ya[f];
        vb += wg * yb[f];
      }
      ((float*)&hva)[q] = fmaxf(va, 0.f) * ea;
      ((float*)&hvb)[q] = fmaxf(vb, 0.f) * eb;
    }
    *(float4*)&h1_s[ia * 68 + g4 * 4] = hva;
    *(float4*)&h1_s[ib * 68 + g4 * 4] = hvb;
  }
  __syncthreads();

  // ---- pass 2: z = e_i * sum_j (win+I)[i][j] * h1e[j]  for 2 rows ----
  float4 za[16], zb[16];
#pragma unroll
  for (int q = 0; q < 16; ++q) {
    za[q] = make_float4(0.f, 0.f, 0.f, 0.f);
    zb[q] = make_float4(0.f, 0.f, 0.f, 0.f);
  }
#pragma unroll 2
  for (int j = 0; j < Nn; ++j) {
    float2 pa = pk[j * Nn + ia];
    float2 pb = pk[j * Nn + ib];
    float va = pa.x * scr + pa.y * ssr;
    float vb = pb.x * scr + pb.y * ssr;
    float wfa = fmaxf(va, 0.f) + ((j == ia) ? 1.f : 0.f);
    float wfb = fmaxf(vb, 0.f) + ((j == ib) ? 1.f : 0.f);
#pragma unroll
    for (int g4 = 0; g4 < 16; ++g4) {
      float4 h4 = *(const float4*)&h1_s[j * 68 + g4 * 4];
      za[g4].x += wfa * h4.x; za[g4].y += wfa * h4.y;
      za[g4].z += wfa * h4.z; za[g4].w += wfa * h4.w;
      zb[g4].x += wfb * h4.x; zb[g4].y += wfb * h4.y;
      zb[g4].z += wfb * h4.z; zb[g4].w += wfb * h4.w;
    }
  }
#pragma unroll
  for (int q = 0; q < 16; ++q) {
    za[q].x *= ea; za[q].y *= ea; za[q].z *= ea; za[q].w *= ea;
    zb[q].x *= eb; zb[q].y *= eb; zb[q].z *= eb; zb[q].w *= eb;
  }
  __syncthreads();   // all pass-2 reads of h1_s done; reuse for sf staging

  // ---- W2 + relu -> staged in h1_s (uniform wgc2T reads) ----
#pragma unroll
  for (int c = 0; c < 4; ++c) {
    float sa[16], sb[16];
#pragma unroll
    for (int q = 0; q < 16; ++q) { sa[q] = bgc2[c * 16 + q]; sb[q] = sa[q]; }
#pragma unroll
    for (int k4 = 0; k4 < 16; ++k4) {
#pragma unroll
      for (int e = 0; e < 4; ++e) {
        int k = k4 * 4 + e;
        float zka = ((const float*)&za[k4])[e];
        float zkb = ((const float*)&zb[k4])[e];
#pragma unroll
        for (int q = 0; q < 16; ++q) {
          float wk = wgc2T[k * Hh + c * 16 + q];
          sa[q] += wk * zka;
          sb[q] += wk * zkb;
        }
      }
    }
#pragma unroll
    for (int q4 = 0; q4 < 4; ++q4) {
      float4 va = make_float4(fmaxf(sa[q4 * 4 + 0], 0.f), fmaxf(sa[q4 * 4 + 1], 0.f),
                              fmaxf(sa[q4 * 4 + 2], 0.f), fmaxf(sa[q4 * 4 + 3], 0.f));
      float4 vb = make_float4(fmaxf(sb[q4 * 4 + 0], 0.f), fmaxf(sb[q4 * 4 + 1], 0.f),
                              fmaxf(sb[q4 * 4 + 2], 0.f), fmaxf(sb[q4 * 4 + 3], 0.f));
      *(float4*)&h1_s[ia * 68 + c * 16 + q4 * 4] = va;
      *(float4*)&h1_s[ib * 68 + c * 16 + q4 * 4] = vb;
    }
  }
  __syncthreads();
  // ---- coalesced store ----
  long base = (long)IDX2(t, b) * Nn * Hh;
  for (int idx = tid; idx < Nn * 16; idx += 128) {
    int j = idx >> 4, g4 = idx & 15;
    *(float4*)&sf_all[base + j * Hh + g4 * 4] = *(const float4*)&h1_s[j * 68 + g4 * 4];
  }
}

// ---------------------------------------------------------------------------
// GI: gi = sf @ W_ih^T + b_ih for TCHUNK timesteps (16 rows/wave, VALU-bound)
// ---------------------------------------------------------------------------
__global__ __launch_bounds__(256) void k_gi(
    const float* __restrict__ sf_all, const float4* __restrict__ wihP,
    const float* __restrict__ bih, float* __restrict__ gi, int t0) {
  __shared__ float sf_c[4][16][64];
  int tid = threadIdx.x, w = tid >> 6, lane = tid & 63;
  int rowc0 = blockIdx.x * 64 + w * 16;
  long rowg0 = (long)t0 * (Bsz * Nn) + rowc0;
#pragma unroll
  for (int rr = 0; rr < 16; ++rr)
    sf_c[w][rr][lane] = sf_all[(rowg0 + rr) * Hh + lane];
  float bi_r = bih[lane], bi_z = bih[64 + lane], bi_n = bih[128 + lane];
  float ar[16], az[16], an[16];
#pragma unroll
  for (int rr = 0; rr < 16; ++rr) { ar[rr] = bi_r; az[rr] = bi_z; an[rr] = bi_n; }
#pragma unroll 2
  for (int kb = 0; kb < 16; ++kb) {
    int k0 = kb * 4;
    float4 wi0 = wihP[(k0 + 0) * 64 + lane];
    float4 wi1 = wihP[(k0 + 1) * 64 + lane];
    float4 wi2 = wihP[(k0 + 2) * 64 + lane];
    float4 wi3 = wihP[(k0 + 3) * 64 + lane];
#pragma unroll
    for (int rr = 0; rr < 16; ++rr) {
      const float4 s4 = *(const float4*)&sf_c[w][rr][k0];
      ar[rr] += s4.x * wi0.x + s4.y * wi1.x + s4.z * wi2.x + s4.w * wi3.x;
      az[rr] += s4.x * wi0.y + s4.y * wi1.y + s4.z * wi2.y + s4.w * wi3.y;
      an[rr] += s4.x * wi0.z + s4.y * wi1.z + s4.z * wi2.z + s4.w * wi3.z;
    }
  }
#pragma unroll
  for (int rr = 0; rr < 16; ++rr) {
    long rowc = rowc0 + rr;
    gi[(rowc * 3 + 0) * 64 + lane] = ar[rr];
    gi[(rowc * 3 + 1) * 64 + lane] = az[rr];
    gi[(rowc * 3 + 2) * 64 + lane] = an[rr];
  }
}

// ---------------------------------------------------------------------------
// GRU scan over one chunk (gh only; whh streamed; h broadcast via LDS rows)
// ---------------------------------------------------------------------------
__global__ __launch_bounds__(256) void k_gru_scan4(
    const float* __restrict__ gi, const float4* __restrict__ whhP,
    const float* __restrict__ bhh, float* __restrict__ hstate,
    int t0, int nt) {
  __shared__ float h_s[16][64];
  int b = blockIdx.x >> 4;
  int i0 = (blockIdx.x & 15) * 16;
  int tid = threadIdx.x, w = tid >> 6, lane = tid & 63;
  float bh_r = bhh[lane], bh_z = bhh[64 + lane], bh_n = bhh[128 + lane];
  float h_reg[4];
#pragma unroll
  for (int rr = 0; rr < 4; ++rr) {
    float hv = (t0 == 0) ? 0.f
                         : hstate[((long)b * Nn + i0 + w * 4 + rr) * Hh + lane];
    h_reg[rr] = hv;
    h_s[w * 4 + rr][lane] = hv;
  }
  for (int tl = 0; tl < nt; ++tl) {
    long rbase = ((long)tl * Bsz + b) * Nn + i0 + w * 4;
    float gr[4], gz[4], gn[4], hr[4], hz[4], hn[4];
#pragma unroll
    for (int rr = 0; rr < 4; ++rr) {
      gr[rr] = gi[((rbase + rr) * 3 + 0) * 64 + lane];
      gz[rr] = gi[((rbase + rr) * 3 + 1) * 64 + lane];
      gn[rr] = gi[((rbase + rr) * 3 + 2) * 64 + lane];
      hr[rr] = bh_r; hz[rr] = bh_z; hn[rr] = bh_n;
    }
#pragma unroll 4
    for (int kb = 0; kb < 16; ++kb) {
      int k0 = kb * 4;
      float4 wh0 = whhP[(k0 + 0) * 64 + lane];
      float4 wh1 = whhP[(k0 + 1) * 64 + lane];
      float4 wh2 = whhP[(k0 + 2) * 64 + lane];
      float4 wh3 = whhP[(k0 + 3) * 64 + lane];
#pragma unroll
      for (int rr = 0; rr < 4; ++rr) {
        const float4 h4 = *(const float4*)&h_s[w * 4 + rr][k0];
        hr[rr] += h4.x * wh0.x + h4.y * wh1.x + h4.z * wh2.x + h4.w * wh3.x;
        hz[rr] += h4.x * wh0.y + h4.y * wh1.y + h4.z * wh2.y + h4.w * wh3.y;
        hn[rr] += h4.x * wh0.z + h4.y * wh1.z + h4.z * wh2.z + h4.w * wh3.z;
      }
    }
#pragma unroll
    for (int rr = 0; rr < 4; ++rr) {
      float rg = 1.f / (1.f + expf(-(gr[rr] + hr[rr])));
      float zg = 1.f / (1.f + expf(-(gz[rr] + hz[rr])));
      float ng = tanhf(gn[rr] + rg * hn[rr]);
      float hv = (1.f - zg) * ng + zg * h_reg[rr];
      h_reg[rr] = hv;
      h_s[w * 4 + rr][lane] = hv;
    }
  }
#pragma unroll
  for (int rr = 0; rr < 4; ++rr)
    hstate[((long)b * Nn + i0 + w * 4 + rr) * Hh + lane] = h_reg[rr];
}

// ---------------------------------------------------------------------------
// MISC: blocks < Bsz*Nn: decoder adjacencies A1d[i][j], A2d[i][j] (row layout).
//       blocks >= Bsz*Nn: dec0 (x0 = mlp(h)).
// ---------------------------------------------------------------------------
__global__ __launch_bounds__(256) void k_misc(
    const float* __restrict__ hw, const float2* __restrict__ pk,
    const float* __restrict__ d23, const float* __restrict__ e23,
    float* __restrict__ A1d, float* __restrict__ A2d,
    const float* __restrict__ hstate,
    const float* __restrict__ wm1T, const float* __restrict__ bm1,
    const float* __restrict__ wm2T, const float* __restrict__ bm2,
    float* __restrict__ xnext) {
  __shared__ float h_lds[16][Hh];
  __shared__ float u_lds[16][M1];
  int tid = threadIdx.x;
  if (blockIdx.x < Bsz * Nn) {
    int b = blockIdx.x >> 8;
    int i = blockIdx.x & 255;
    int j = tid;
    float spd = hw[(b * Tt + (Tt - 1)) * Fw + 2];
    float rad = hw[(b * Tt + (Tt - 1)) * Fw + 1] * DEG2RAD;
    float cr = cosf(rad), sr = sinf(rad);
    const float* drow = d23 + b * Nn;
    const float* erow = e23 + b * Nn;
    float2 pv = pk[i * Nn + j];
    float val = spd * (pv.x * cr + pv.y * sr);
    float dlt = (j == i) ? 1.f : 0.f;
    float wout = fmaxf(val, 0.f);
    float win  = (j == i) ? wout : fmaxf(-val, 0.f);
    A1d[((long)b * Nn + i) * Nn + j] = drow[i] * (wout + dlt) * drow[j];
    A2d[((long)b * Nn + i) * Nn + j] = erow[i] * (win + dlt) * erow[j];
    return;
  }
  int r0 = (blockIdx.x - Bsz * Nn) * 16;
#pragma unroll
  for (int c = 0; c < 4; ++c) {
    int idx = tid + c * 256;
    h_lds[idx >> 6][idx & 63] = hstate[(long)r0 * Hh + idx];
  }
  __syncthreads();
#pragma unroll
  for (int rep = 0; rep < 2; ++rep) {
    int idx = tid + rep * 256;
    int row = idx >> 5, m = idx & 31;
    float um = bm1[m];
    for (int k = 0; k < Hh; ++k) um += wm1T[k * M1 + m] * h_lds[row][k];
    u_lds[row][m] = fmaxf(um, 0.f);
  }
  __syncthreads();
  if (tid < 16 * Fp) {
    int row = tid / Fp, f = tid % Fp;
    float pf = bm2[f];
#pragma unroll
    for (int m = 0; m < M1; ++m) pf += wm2T[m * Fp + f] * u_lds[row][m];
    xnext[(r0 + row) * Fp + f] = pf;
  }
}

// ---------------------------------------------------------------------------
// Ddec A: gconv1 for decoder (A1d rows, shuffle reduce) -> h1d
// ---------------------------------------------------------------------------
__global__ __launch_bounds__(256) void k_dstep_A(
    const float* __restrict__ xb, const float* __restrict__ A1d,
    const float* __restrict__ wgc1, const float* __restrict__ bgc1,
    float* __restrict__ h1d) {
  __shared__ float x_lds[Nn * Fp];
  int b = blockIdx.x >> 4;
  int i0 = (blockIdx.x & 15) * 16;
  int tid = threadIdx.x, w = tid >> 6, lane = tid & 63;
  const float* xsrc = xb + (long)b * Nn * Fp;
#pragma unroll
  for (int c = 0; c < 6; ++c) x_lds[tid + 256 * c] = xsrc[tid + 256 * c];
  __syncthreads();
#pragma unroll
  for (int rr = 0; rr < 4; ++rr) {
    int i = i0 + w * 4 + rr;
    const float* arow = A1d + ((long)b * Nn + i) * Nn;
    float acc[Fp] = {0.f, 0.f, 0.f, 0.f, 0.f, 0.f};
#pragma unroll
    for (int c = 0; c < 4; ++c) {
      int j = lane + 64 * c;
      float wt = arow[j];
#pragma unroll
      for (int f = 0; f < Fp; ++f) acc[f] += wt * x_lds[j * Fp + f];
    }
#pragma unroll
    for (int f = 0; f < Fp; ++f) {
#pragma unroll
      for (int off = 32; off; off >>= 1) acc[f] += __shfl_xor(acc[f], off);
    }
    float hv = bgc1[lane];
#pragma unroll
    for (int f = 0; f < Fp; ++f) hv += wgc1[lane * Fp + f] * acc[f];
    h1d[((long)b * Nn + i) * Hh + lane] = fmaxf(hv, 0.f);
  }
}

// ---------------------------------------------------------------------------
// Ddec B: gconv2 + W2 + GRU (streamed weights) + MLP -> out, xnext
// ---------------------------------------------------------------------------
__global__ __launch_bounds__(256) void k_dstep_B(
    const float* __restrict__ A2d, const float* __restrict__ h1d,
    const float* __restrict__ wgc2T, const float* __restrict__ bgc2,
    const float4* __restrict__ wihP, const float4* __restrict__ whhP,
    const float* __restrict__ bih, const float* __restrict__ bhh,
    float* __restrict__ hstate,
    const float* __restrict__ wm1T, const float* __restrict__ bm1,
    const float* __restrict__ wm2T, const float* __restrict__ bm2,
    float* __restrict__ outp, float* __restrict__ xnext, int p) {
  __shared__ __align__(16) float wvT[Nn * 20];
  __shared__ float red[4][16][Hh];
  __shared__ float y2[16][Hh];
  __shared__ float sf_s[16][Hh];
  __shared__ float h_s[16][Hh];
  __shared__ float hn_lds[16][Hh];
  __shared__ float u_lds[16][M1];
  int b = blockIdx.x >> 4;
  int i0 = (blockIdx.x & 15) * 16;
  int tid = threadIdx.x, w = tid >> 6, lane = tid & 63;

#pragma unroll
  for (int r = 0; r < 16; ++r)
    wvT[tid * 20 + r] = A2d[((long)b * Nn + i0 + r) * Nn + tid];
  float hp_reg[4];
#pragma unroll
  for (int rr = 0; rr < 4; ++rr) {
    hp_reg[rr] = hstate[((long)b * Nn + i0 + w * 4 + rr) * Hh + lane];
    h_s[w * 4 + rr][lane] = hp_reg[rr];
  }
  __syncthreads();

  float acc[16];
#pragma unroll
  for (int r = 0; r < 16; ++r) acc[r] = 0.f;
  const float* h1b = h1d + (long)b * Nn * Hh;
#pragma unroll 4
  for (int jj = 0; jj < 64; ++jj) {
    int j = w * 64 + jj;
    float hv = h1b[j * Hh + lane];
    const float4* wp = (const float4*)(wvT + j * 20);
    float4 w0 = wp[0], w1 = wp[1], w2 = wp[2], w3 = wp[3];
    acc[0] += w0.x * hv; acc[1] += w0.y * hv; acc[2] += w0.z * hv; acc[3] += w0.w * hv;
    acc[4] += w1.x * hv; acc[5] += w1.y * hv; acc[6] += w1.z * hv; acc[7] += w1.w * hv;
    acc[8] += w2.x * hv; acc[9] += w2.y * hv; acc[10] += w2.z * hv; acc[11] += w2.w * hv;
    acc[12] += w3.x * hv; acc[13] += w3.y * hv; acc[14] += w3.z * hv; acc[15] += w3.w * hv;
  }
#pragma unroll
  for (int r = 0; r < 16; ++r) red[w][r][lane] = acc[r];
  __syncthreads();
#pragma unroll
  for (int rr = 0; rr < 4; ++rr) {
    int r = w * 4 + rr;
    y2[r][lane] = red[0][r][lane] + red[1][r][lane] + red[2][r][lane] + red[3][r][lane];
  }
  {
    float a0 = bgc2[lane], a1 = a0, a2 = a0, a3 = a0;
    for (int k = 0; k < Hh; ++k) {
      float wk = wgc2T[k * Hh + lane];
      a0 += wk * y2[w * 4 + 0][k];
      a1 += wk * y2[w * 4 + 1][k];
      a2 += wk * y2[w * 4 + 2][k];
      a3 += wk * y2[w * 4 + 3][k];
    }
    sf_s[w * 4 + 0][lane] = fmaxf(a0, 0.f);
    sf_s[w * 4 + 1][lane] = fmaxf(a1, 0.f);
    sf_s[w * 4 + 2][lane] = fmaxf(a2, 0.f);
    sf_s[w * 4 + 3][lane] = fmaxf(a3, 0.f);
  }

  float hn_reg[4];
  {
    float bi_r = bih[lane], bi_z = bih[64 + lane], bi_n = bih[128 + lane];
    float bh_r = bhh[lane], bh_z = bhh[64 + lane], bh_n = bhh[128 + lane];
    float gir[4], giz[4], gin[4], ghr[4], ghz[4], ghn[4];
#pragma unroll
    for (int rr = 0; rr < 4; ++rr) {
      gir[rr] = bi_r; giz[rr] = bi_z; gin[rr] = bi_n;
      ghr[rr] = bh_r; ghz[rr] = bh_z; ghn[rr] = bh_n;
    }
#pragma unroll 4
    for (int kb = 0; kb < 16; ++kb) {
      int k0 = kb * 4;
      float4 wi[4], wh[4];
#pragma unroll
      for (int q = 0; q < 4; ++q) {
        wi[q] = wihP[(k0 + q) * 64 + lane];
        wh[q] = whhP[(k0 + q) * 64 + lane];
      }
#pragma unroll
      for (int rr = 0; rr < 4; ++rr) {
        const float4 s4 = *(const float4*)&sf_s[w * 4 + rr][k0];
        const float4 h4 = *(const float4*)&h_s[w * 4 + rr][k0];
        gir[rr] += s4.x * wi[0].x + s4.y * wi[1].x + s4.z * wi[2].x + s4.w * wi[3].x;
        giz[rr] += s4.x * wi[0].y + s4.y * wi[1].y + s4.z * wi[2].y + s4.w * wi[3].y;
        gin[rr] += s4.x * wi[0].z + s4.y * wi[1].z + s4.z * wi[2].z + s4.w * wi[3].z;
        ghr[rr] += h4.x * wh[0].x + h4.y * wh[1].x + h4.z * wh[2].x + h4.w * wh[3].x;
        ghz[rr] += h4.x * wh[0].y + h4.y * wh[1].y + h4.z * wh[2].y + h4.w * wh[3].y;
        ghn[rr] += h4.x * wh[0].z + h4.y * wh[1].z + h4.z * wh[2].z + h4.w * wh[3].z;
      }
    }
#pragma unroll
    for (int rr = 0; rr < 4; ++rr) {
      float rg = 1.f / (1.f + expf(-(gir[rr] + ghr[rr])));
      float zg = 1.f / (1.f + expf(-(giz[rr] + ghz[rr])));
      float ng = tanhf(gin[rr] + rg * ghn[rr]);
      hn_reg[rr] = (1.f - zg) * ng + zg * hp_reg[rr];
      hstate[((long)b * Nn + i0 + w * 4 + rr) * Hh + lane] = hn_reg[rr];
      hn_lds[w * 4 + rr][lane] = hn_reg[rr];
    }
  }
  __syncthreads();
#pragma unroll
  for (int rep = 0; rep < 2; ++rep) {
    int idx = tid + rep * 256;
    int row = idx >> 5, m = idx & 31;
    float um = bm1[m];
    for (int k = 0; k < Hh; ++k) um += wm1T[k * M1 + m] * hn_lds[row][k];
    u_lds[row][m] = fmaxf(um, 0.f);
  }
  __syncthreads();
  if (tid < 16 * Fp) {
    int row = tid / Fp, f = tid % Fp;
    float pf = bm2[f];
#pragma unroll
    for (int m = 0; m < M1; ++m) pf += wm2T[m * Fp + f] * u_lds[row][m];
    int i = i0 + row;
    outp[(((long)b * PredL + p) * Nn + i) * Fp + f] = pf;
    xnext[((long)b * Nn + i) * Fp + f] = pf;
  }
}

// ---------------------------------------------------------------------------
extern "C" void kernel_launch(void* const* d_in, const int* in_sizes, int n_in,
                              void* d_out, int out_size, void* d_ws, size_t ws_size,
                              hipStream_t stream) {
  const float* hp     = (const float*)d_in[0];
  const float* hw     = (const float*)d_in[1];
  const float* adj    = (const float*)d_in[2];
  const float* coords = (const float*)d_in[3];
  const float* wgc1   = (const float*)d_in[4];
  const float* bgc1   = (const float*)d_in[5];
  const float* wgc2   = (const float*)d_in[6];
  const float* bgc2   = (const float*)d_in[7];
  const float* wih    = (const float*)d_in[8];
  const float* whh    = (const float*)d_in[9];
  const float* bih    = (const float*)d_in[10];
  const float* bhh    = (const float*)d_in[11];
  const float* wm1    = (const float*)d_in[12];
  const float* bm1    = (const float*)d_in[13];
  const float* wm2    = (const float*)d_in[14];
  const float* bm2    = (const float*)d_in[15];
  float* out = (float*)d_out;

  float* w = (float*)d_ws;
  float2* pk    = (float2*)w; w += Nn * Nn * 2;
  float* d23    = w; w += Bsz * Nn;
  float* e23    = w; w += Bsz * Nn;
  float* hstate = w; w += Bsz * Nn * Hh;
  float* sf_all = w; w += (long)Tt * Bsz * Nn * Hh;
  float* gi_ch  = w; w += (long)TCHUNK * Bsz * Nn * 3 * 64;
  float* h1d    = w; w += Bsz * Nn * Hh;
  float* xb0    = w; w += Bsz * Nn * Fp;
  float* xb1    = w; w += Bsz * Nn * Fp;
  float* A1d    = w; w += Bsz * Nn * Nn;
  float* A2d    = w; w += Bsz * Nn * Nn;
  float* wgc2T  = w; w += Hh * Hh;
  float* wm1T   = w; w += Hh * M1;
  float* wm2T   = w; w += M1 * Fp;
  float4* wihP  = (float4*)w; w += Hh * 64 * 4;
  float4* whhP  = (float4*)w; w += Hh * 64 * 4;

  k_prep<<<Nn + 1, 256, 0, stream>>>(coords, adj, wgc2, wih, whh, wm1, wm2,
                                     pk, wgc2T, wm1T, wm2T, wihP, whhP);
  k_enc<<<Tt * Bsz, 128, 0, stream>>>(pk, hp, hw, wgc1, bgc1, wgc2T, bgc2,
                                      sf_all, d23, e23);
  for (int s = 0; s < Tt / TCHUNK; ++s) {
    int t0 = s * TCHUNK;
    k_gi<<<(TCHUNK * Bsz * Nn) / 64, 256, 0, stream>>>(sf_all, wihP, bih,
                                                       gi_ch, t0);
    k_gru_scan4<<<Bsz * 16, 256, 0, stream>>>(gi_ch, whhP, bhh, hstate,
                                              t0, TCHUNK);
  }
  k_misc<<<Bsz * Nn + Bsz * Nn / 16, 256, 0, stream>>>(
      hw, pk, d23, e23, A1d, A2d, hstate, wm1T, bm1, wm2T, bm2, xb0);

  for (int p = 0; p < PredL; ++p) {
    float* xin  = (p & 1) ? xb1 : xb0;
    float* xout = (p & 1) ? xb0 : xb1;
    k_dstep_A<<<Bsz * 16, 256, 0, stream>>>(xin, A1d, wgc1, bgc1, h1d);
    k_dstep_B<<<Bsz * 16, 256, 0, stream>>>(
        A2d, h1d, wgc2T, bgc2, wihP, whhP, bih, bhh, hstate,
        wm1T, bm1, wm2T, bm2, out, xout, p);
  }
}

// Round 12
// 659.363 us; speedup vs baseline: 1.7669x; 1.2402x over previous
//
#include <hip/hip_runtime.h>
#include <math.h>

#define Bsz 16
#define Tt 24
#define Nn 256
#define Fp 6
#define Hh 64
#define PredL 12
#define Fw 4
#define M1 32
#define TCHUNK 12
#define DEG2RAD 0.017453292519943295f
#define IDX2(t, b) ((t) * Bsz + (b))

// ---------------------------------------------------------------------------
// P0+PT: blocks 0..255 build packed pk[i][j] = {Ac,As}; block 256 repacks
// weights (wgc2T[k][g], wm1T, wm2T, wihP/whhP float4 {r,z,n,0} per [k][lane]).
// ---------------------------------------------------------------------------
__global__ __launch_bounds__(256) void k_prep(
    const float* __restrict__ coords, const float* __restrict__ adj,
    const float* __restrict__ wgc2, const float* __restrict__ wih,
    const float* __restrict__ whh,  const float* __restrict__ wm1,
    const float* __restrict__ wm2,
    float2* __restrict__ pk,
    float* __restrict__ wgc2T, float* __restrict__ wm1T, float* __restrict__ wm2T,
    float4* __restrict__ wihP, float4* __restrict__ whhP) {
  int tid = threadIdx.x;
  if (blockIdx.x < Nn) {
    int i = blockIdx.x;
    int j = tid;
    float dx = coords[2 * j]     - coords[2 * i];
    float dy = coords[2 * j + 1] - coords[2 * i + 1];
    float ang = atan2f(dy, dx);
    float a = adj[i * Nn + j];
    pk[i * Nn + j] = make_float2(a * cosf(ang), a * sinf(ang));
    return;
  }
  for (int idx = tid; idx < Hh * Hh; idx += 256) {
    int g = idx / Hh, k = idx % Hh;
    wgc2T[k * Hh + g] = wgc2[g * Hh + k];
  }
  for (int idx = tid; idx < M1 * Hh; idx += 256) {
    int m = idx / Hh, k = idx % Hh;
    wm1T[k * M1 + m] = wm1[m * Hh + k];
  }
  for (int idx = tid; idx < Fp * M1; idx += 256) {
    int f = idx / M1, m = idx % M1;
    wm2T[m * Fp + f] = wm2[f * M1 + m];
  }
  for (int idx = tid; idx < Hh * 64; idx += 256) {
    int k = idx >> 6, lane = idx & 63;
    wihP[idx] = make_float4(wih[(0 * 64 + lane) * Hh + k],
                            wih[(1 * 64 + lane) * Hh + k],
                            wih[(2 * 64 + lane) * Hh + k], 0.f);
    whhP[idx] = make_float4(whh[(0 * 64 + lane) * Hh + k],
                            whh[(1 * 64 + lane) * Hh + k],
                            whh[(2 * 64 + lane) * Hh + k], 0.f);
  }
}

// ---------------------------------------------------------------------------
// E: fused encoder (round-9 measured 153us form): deg + gconv1 + gconv2 + W2
// -> sf_all. One block per (t,b), 256 threads, thread = row.
// ---------------------------------------------------------------------------
__global__ __launch_bounds__(256) void k_enc(
    const float2* __restrict__ pk, const float* __restrict__ hp,
    const float* __restrict__ hw,
    const float* __restrict__ wgc1, const float* __restrict__ bgc1,
    const float* __restrict__ wgc2T, const float* __restrict__ bgc2,
    float* __restrict__ sf_all,
    float* __restrict__ d23, float* __restrict__ e23) {
  __shared__ float d_lds[Nn];
  __shared__ float e_lds[Nn];
  __shared__ __align__(16) float u_s[Nn * 8];     // 8KB
  __shared__ __align__(16) float h1_s[Nn * 68];   // 69.6KB
  int tb = blockIdx.x, t = tb / Bsz, b = tb % Bsz;
  int tid = threadIdx.x;
  int i = tid;
  float spd = hw[(b * Tt + t) * Fw + 2];
  float rad = hw[(b * Tt + t) * Fw + 1] * DEG2RAD;
  float scr = spd * cosf(rad), ssr = spd * sinf(rad);

  // ---- pass 0: degrees (from column i of pk) ----
  {
    float rs = 0.f, cs = 0.f;
#pragma unroll 4
    for (int j = 0; j < Nn; ++j) {
      float2 pv = pk[j * Nn + i];
      float v = pv.x * scr + pv.y * ssr;   // V(j,i)
      cs += fmaxf(v, 0.f);
      rs += fmaxf(-v, 0.f);
    }
    float2 pd = pk[i * Nn + i];
    float vii = pd.x * scr + pd.y * ssr;
    rs += vii;  // diag fix
    float di = 1.f / (sqrtf(rs + 1.f) + 1e-6f);
    float ei = 1.f / (sqrtf(cs + 1.f) + 1e-6f);
    d_lds[i] = di; e_lds[i] = ei;
    if (t == Tt - 1) { d23[b * Nn + i] = di; e23[b * Nn + i] = ei; }
  }
  __syncthreads();

  // ---- stage u = d_j * x ----
  {
    const float* xsrc = hp + (long)(b * Tt + t) * Nn * Fp;
    for (int idx = tid; idx < Nn * Fp; idx += 256) {
      int j = idx / Fp, f = idx - j * Fp;
      u_s[j * 8 + f] = d_lds[j] * xsrc[idx];
    }
    u_s[tid * 8 + 6] = 0.f;
    u_s[tid * 8 + 7] = 0.f;
  }
  __syncthreads();

  // ---- pass 1: gconv1 for row i; e-scaled h1 row -> LDS ----
  {
    float a0 = 0.f, a1 = 0.f, a2 = 0.f, a3 = 0.f, a4 = 0.f, a5 = 0.f;
#pragma unroll 2
    for (int j = 0; j < Nn; ++j) {
      float2 pv = pk[j * Nn + i];
      float v = pv.x * scr + pv.y * ssr;
      float w = fmaxf(-v, 0.f);            // wout[i][j], wrong on diag
      float4 ul = *(const float4*)&u_s[j * 8];
      float4 uh = *(const float4*)&u_s[j * 8 + 4];
      a0 += w * ul.x; a1 += w * ul.y; a2 += w * ul.z;
      a3 += w * ul.w; a4 += w * uh.x; a5 += w * uh.y;
    }
    float2 pd = pk[i * Nn + i];
    float vii = pd.x * scr + pd.y * ssr;
    float di = d_lds[i], ei = e_lds[i];
    float c1 = vii + 1.f;  // diag fix + identity
    float y0 = di * (a0 + c1 * u_s[i * 8 + 0]);
    float y1 = di * (a1 + c1 * u_s[i * 8 + 1]);
    float y2 = di * (a2 + c1 * u_s[i * 8 + 2]);
    float y3 = di * (a3 + c1 * u_s[i * 8 + 3]);
    float y4 = di * (a4 + c1 * u_s[i * 8 + 4]);
    float y5 = di * (a5 + c1 * u_s[i * 8 + 5]);
#pragma unroll
    for (int g4 = 0; g4 < 16; ++g4) {
      float4 hv;
#pragma unroll
      for (int q = 0; q < 4; ++q) {
        int g = g4 * 4 + q;
        float v2 = bgc1[g] + wgc1[g * Fp + 0] * y0 + wgc1[g * Fp + 1] * y1 +
                   wgc1[g * Fp + 2] * y2 + wgc1[g * Fp + 3] * y3 +
                   wgc1[g * Fp + 4] * y4 + wgc1[g * Fp + 5] * y5;
        ((float*)&hv)[q] = fmaxf(v2, 0.f) * ei;
      }
      *(float4*)&h1_s[i * 68 + g4 * 4] = hv;
    }
  }
  __syncthreads();

  // ---- pass 2: z[i][g] = e_i * sum_j (win+I)[i][j] h1e[j] ----
  float z[64];
#pragma unroll
  for (int k = 0; k < 64; ++k) z[k] = 0.f;
#pragma unroll 2
  for (int j = 0; j < Nn; ++j) {
    float2 pv = pk[j * Nn + i];
    float v = pv.x * scr + pv.y * ssr;     // V(j,i)
    float wf = fmaxf(v, 0.f) + ((j == i) ? 1.f : 0.f);
#pragma unroll
    for (int g4 = 0; g4 < 16; ++g4) {
      float4 h4 = *(const float4*)&h1_s[j * 68 + g4 * 4];
      z[g4 * 4 + 0] += wf * h4.x;
      z[g4 * 4 + 1] += wf * h4.y;
      z[g4 * 4 + 2] += wf * h4.z;
      z[g4 * 4 + 3] += wf * h4.w;
    }
  }
  {
    float ei = e_lds[i];
#pragma unroll
    for (int k = 0; k < 64; ++k) z[k] *= ei;
  }
  __syncthreads();   // h1_s free; reuse for sf staging

  // ---- W2 + relu -> staged in h1_s, then coalesced store ----
#pragma unroll
  for (int c = 0; c < 4; ++c) {
    float s[16];
#pragma unroll
    for (int q = 0; q < 16; ++q) s[q] = bgc2[c * 16 + q];
#pragma unroll
    for (int k = 0; k < 64; ++k) {
      float zk = z[k];
#pragma unroll
      for (int q = 0; q < 16; ++q) s[q] += wgc2T[k * Hh + c * 16 + q] * zk;
    }
#pragma unroll
    for (int q4 = 0; q4 < 4; ++q4) {
      float4 sv = make_float4(fmaxf(s[q4 * 4 + 0], 0.f), fmaxf(s[q4 * 4 + 1], 0.f),
                              fmaxf(s[q4 * 4 + 2], 0.f), fmaxf(s[q4 * 4 + 3], 0.f));
      *(float4*)&h1_s[i * 68 + c * 16 + q4 * 4] = sv;
    }
  }
  __syncthreads();
  long base = (long)IDX2(t, b) * Nn * Hh;
  for (int idx = tid; idx < Nn * 16; idx += 256) {
    int j = idx >> 4, g4 = idx & 15;
    *(float4*)&sf_all[base + j * Hh + g4 * 4] = *(const float4*)&h1_s[j * 68 + g4 * 4];
  }
}

// ---------------------------------------------------------------------------
// GI: gi = sf @ W_ih^T + b_ih for TCHUNK timesteps (16 rows/wave, VALU-bound)
// ---------------------------------------------------------------------------
__global__ __launch_bounds__(256) void k_gi(
    const float* __restrict__ sf_all, const float4* __restrict__ wihP,
    const float* __restrict__ bih, float* __restrict__ gi, int t0) {
  __shared__ float sf_c[4][16][64];
  int tid = threadIdx.x, w = tid >> 6, lane = tid & 63;
  int rowc0 = blockIdx.x * 64 + w * 16;
  long rowg0 = (long)t0 * (Bsz * Nn) + rowc0;
#pragma unroll
  for (int rr = 0; rr < 16; ++rr)
    sf_c[w][rr][lane] = sf_all[(rowg0 + rr) * Hh + lane];
  float bi_r = bih[lane], bi_z = bih[64 + lane], bi_n = bih[128 + lane];
  float ar[16], az[16], an[16];
#pragma unroll
  for (int rr = 0; rr < 16; ++rr) { ar[rr] = bi_r; az[rr] = bi_z; an[rr] = bi_n; }
#pragma unroll 2
  for (int kb = 0; kb < 16; ++kb) {
    int k0 = kb * 4;
    float4 wi0 = wihP[(k0 + 0) * 64 + lane];
    float4 wi1 = wihP[(k0 + 1) * 64 + lane];
    float4 wi2 = wihP[(k0 + 2) * 64 + lane];
    float4 wi3 = wihP[(k0 + 3) * 64 + lane];
#pragma unroll
    for (int rr = 0; rr < 16; ++rr) {
      const float4 s4 = *(const float4*)&sf_c[w][rr][k0];
      ar[rr] += s4.x * wi0.x + s4.y * wi1.x + s4.z * wi2.x + s4.w * wi3.x;
      az[rr] += s4.x * wi0.y + s4.y * wi1.y + s4.z * wi2.y + s4.w * wi3.y;
      an[rr] += s4.x * wi0.z + s4.y * wi1.z + s4.z * wi2.z + s4.w * wi3.z;
    }
  }
#pragma unroll
  for (int rr = 0; rr < 16; ++rr) {
    long rowc = rowc0 + rr;
    gi[(rowc * 3 + 0) * 64 + lane] = ar[rr];
    gi[(rowc * 3 + 1) * 64 + lane] = az[rr];
    gi[(rowc * 3 + 2) * 64 + lane] = an[rr];
  }
}

// ---------------------------------------------------------------------------
// GRU scan over one chunk (gh only; whh streamed; h broadcast via LDS rows)
// ---------------------------------------------------------------------------
__global__ __launch_bounds__(256) void k_gru_scan4(
    const float* __restrict__ gi, const float4* __restrict__ whhP,
    const float* __restrict__ bhh, float* __restrict__ hstate,
    int t0, int nt) {
  __shared__ float h_s[16][64];
  int b = blockIdx.x >> 4;
  int i0 = (blockIdx.x & 15) * 16;
  int tid = threadIdx.x, w = tid >> 6, lane = tid & 63;
  float bh_r = bhh[lane], bh_z = bhh[64 + lane], bh_n = bhh[128 + lane];
  float h_reg[4];
#pragma unroll
  for (int rr = 0; rr < 4; ++rr) {
    float hv = (t0 == 0) ? 0.f
                         : hstate[((long)b * Nn + i0 + w * 4 + rr) * Hh + lane];
    h_reg[rr] = hv;
    h_s[w * 4 + rr][lane] = hv;
  }
  for (int tl = 0; tl < nt; ++tl) {
    long rbase = ((long)tl * Bsz + b) * Nn + i0 + w * 4;
    float gr[4], gz[4], gn[4], hr[4], hz[4], hn[4];
#pragma unroll
    for (int rr = 0; rr < 4; ++rr) {
      gr[rr] = gi[((rbase + rr) * 3 + 0) * 64 + lane];
      gz[rr] = gi[((rbase + rr) * 3 + 1) * 64 + lane];
      gn[rr] = gi[((rbase + rr) * 3 + 2) * 64 + lane];
      hr[rr] = bh_r; hz[rr] = bh_z; hn[rr] = bh_n;
    }
#pragma unroll 4
    for (int kb = 0; kb < 16; ++kb) {
      int k0 = kb * 4;
      float4 wh0 = whhP[(k0 + 0) * 64 + lane];
      float4 wh1 = whhP[(k0 + 1) * 64 + lane];
      float4 wh2 = whhP[(k0 + 2) * 64 + lane];
      float4 wh3 = whhP[(k0 + 3) * 64 + lane];
#pragma unroll
      for (int rr = 0; rr < 4; ++rr) {
        const float4 h4 = *(const float4*)&h_s[w * 4 + rr][k0];
        hr[rr] += h4.x * wh0.x + h4.y * wh1.x + h4.z * wh2.x + h4.w * wh3.x;
        hz[rr] += h4.x * wh0.y + h4.y * wh1.y + h4.z * wh2.y + h4.w * wh3.y;
        hn[rr] += h4.x * wh0.z + h4.y * wh1.z + h4.z * wh2.z + h4.w * wh3.z;
      }
    }
#pragma unroll
    for (int rr = 0; rr < 4; ++rr) {
      float rg = 1.f / (1.f + expf(-(gr[rr] + hr[rr])));
      float zg = 1.f / (1.f + expf(-(gz[rr] + hz[rr])));
      float ng = tanhf(gn[rr] + rg * hn[rr]);
      float hv = (1.f - zg) * ng + zg * h_reg[rr];
      h_reg[rr] = hv;
      h_s[w * 4 + rr][lane] = hv;
    }
  }
#pragma unroll
  for (int rr = 0; rr < 4; ++rr)
    hstate[((long)b * Nn + i0 + w * 4 + rr) * Hh + lane] = h_reg[rr];
}

// ---------------------------------------------------------------------------
// MISC: blocks < Bsz*Nn: decoder adjacencies A1d[i][j], A2d[i][j] (row layout).
//       blocks >= Bsz*Nn: dec0 (x0 = mlp(h)).
// ---------------------------------------------------------------------------
__global__ __launch_bounds__(256) void k_misc(
    const float* __restrict__ hw, const float2* __restrict__ pk,
    const float* __restrict__ d23, const float* __restrict__ e23,
    float* __restrict__ A1d, float* __restrict__ A2d,
    const float* __restrict__ hstate,
    const float* __restrict__ wm1T, const float* __restrict__ bm1,
    const float* __restrict__ wm2T, const float* __restrict__ bm2,
    float* __restrict__ xnext) {
  __shared__ float h_lds[16][Hh];
  __shared__ float u_lds[16][M1];
  int tid = threadIdx.x;
  if (blockIdx.x < Bsz * Nn) {
    int b = blockIdx.x >> 8;
    int i = blockIdx.x & 255;
    int j = tid;
    float spd = hw[(b * Tt + (Tt - 1)) * Fw + 2];
    float rad = hw[(b * Tt + (Tt - 1)) * Fw + 1] * DEG2RAD;
    float cr = cosf(rad), sr = sinf(rad);
    const float* drow = d23 + b * Nn;
    const float* erow = e23 + b * Nn;
    float2 pv = pk[i * Nn + j];
    float val = spd * (pv.x * cr + pv.y * sr);
    float dlt = (j == i) ? 1.f : 0.f;
    float wout = fmaxf(val, 0.f);
    float win  = (j == i) ? wout : fmaxf(-val, 0.f);
    A1d[((long)b * Nn + i) * Nn + j] = drow[i] * (wout + dlt) * drow[j];
    A2d[((long)b * Nn + i) * Nn + j] = erow[i] * (win + dlt) * erow[j];
    return;
  }
  int r0 = (blockIdx.x - Bsz * Nn) * 16;
#pragma unroll
  for (int c = 0; c < 4; ++c) {
    int idx = tid + c * 256;
    h_lds[idx >> 6][idx & 63] = hstate[(long)r0 * Hh + idx];
  }
  __syncthreads();
#pragma unroll
  for (int rep = 0; rep < 2; ++rep) {
    int idx = tid + rep * 256;
    int row = idx >> 5, m = idx & 31;
    float um = bm1[m];
    for (int k = 0; k < Hh; ++k) um += wm1T[k * M1 + m] * h_lds[row][k];
    u_lds[row][m] = fmaxf(um, 0.f);
  }
  __syncthreads();
  if (tid < 16 * Fp) {
    int row = tid / Fp, f = tid % Fp;
    float pf = bm2[f];
#pragma unroll
    for (int m = 0; m < M1; ++m) pf += wm2T[m * Fp + f] * u_lds[row][m];
    xnext[(r0 + row) * Fp + f] = pf;
  }
}

// ---------------------------------------------------------------------------
// Ddec A: gconv1 for decoder. 512 blocks (8 rows each) -> 2+ blocks/CU.
// ---------------------------------------------------------------------------
__global__ __launch_bounds__(256) void k_dstep_A(
    const float* __restrict__ xb, const float* __restrict__ A1d,
    const float* __restrict__ wgc1, const float* __restrict__ bgc1,
    float* __restrict__ h1d) {
  __shared__ float x_lds[Nn * Fp];
  int b = blockIdx.x >> 5;
  int i0 = (blockIdx.x & 31) * 8;
  int tid = threadIdx.x, w = tid >> 6, lane = tid & 63;
  const float* xsrc = xb + (long)b * Nn * Fp;
#pragma unroll
  for (int c = 0; c < 6; ++c) x_lds[tid + 256 * c] = xsrc[tid + 256 * c];
  __syncthreads();
#pragma unroll
  for (int rr = 0; rr < 2; ++rr) {
    int i = i0 + w * 2 + rr;
    const float* arow = A1d + ((long)b * Nn + i) * Nn;
    float acc[Fp] = {0.f, 0.f, 0.f, 0.f, 0.f, 0.f};
#pragma unroll
    for (int c = 0; c < 4; ++c) {
      int j = lane + 64 * c;
      float wt = arow[j];
#pragma unroll
      for (int f = 0; f < Fp; ++f) acc[f] += wt * x_lds[j * Fp + f];
    }
#pragma unroll
    for (int f = 0; f < Fp; ++f) {
#pragma unroll
      for (int off = 32; off; off >>= 1) acc[f] += __shfl_xor(acc[f], off);
    }
    float hv = bgc1[lane];
#pragma unroll
    for (int f = 0; f < Fp; ++f) hv += wgc1[lane * Fp + f] * acc[f];
    h1d[((long)b * Nn + i) * Hh + lane] = fmaxf(hv, 0.f);
  }
}

// ---------------------------------------------------------------------------
// Ddec B: gconv2 + W2 + GRU + MLP. 512 blocks (8 rows each), ~29KB LDS ->
// 2 blocks/CU co-resident for latency overlap.
// ---------------------------------------------------------------------------
__global__ __launch_bounds__(256) void k_dstep_B(
    const float* __restrict__ A2d, const float* __restrict__ h1d,
    const float* __restrict__ wgc2T, const float* __restrict__ bgc2,
    const float4* __restrict__ wihP, const float4* __restrict__ whhP,
    const float* __restrict__ bih, const float* __restrict__ bhh,
    float* __restrict__ hstate,
    const float* __restrict__ wm1T, const float* __restrict__ bm1,
    const float* __restrict__ wm2T, const float* __restrict__ bm2,
    float* __restrict__ outp, float* __restrict__ xnext, int p) {
  __shared__ __align__(16) float wvT[Nn * 12];   // 12KB (8 used + 4 pad)
  __shared__ float red[4][8][Hh];                // 8KB
  __shared__ float y2[8][Hh];
  __shared__ float sf_s[8][Hh];
  __shared__ float h_s[8][Hh];
  __shared__ float hn_lds[8][Hh];
  __shared__ float u_lds[8][M1];
  int b = blockIdx.x >> 5;
  int i0 = (blockIdx.x & 31) * 8;
  int tid = threadIdx.x, w = tid >> 6, lane = tid & 63;

#pragma unroll
  for (int r = 0; r < 8; ++r)
    wvT[tid * 12 + r] = A2d[((long)b * Nn + i0 + r) * Nn + tid];
  float hp_reg[2];
#pragma unroll
  for (int rr = 0; rr < 2; ++rr) {
    hp_reg[rr] = hstate[((long)b * Nn + i0 + w * 2 + rr) * Hh + lane];
    h_s[w * 2 + rr][lane] = hp_reg[rr];
  }
  __syncthreads();

  float acc[8];
#pragma unroll
  for (int r = 0; r < 8; ++r) acc[r] = 0.f;
  const float* h1b = h1d + (long)b * Nn * Hh;
#pragma unroll 4
  for (int jj = 0; jj < 64; ++jj) {
    int j = w * 64 + jj;
    float hv = h1b[j * Hh + lane];
    float4 w0 = *(const float4*)&wvT[j * 12];
    float4 w1 = *(const float4*)&wvT[j * 12 + 4];
    acc[0] += w0.x * hv; acc[1] += w0.y * hv; acc[2] += w0.z * hv; acc[3] += w0.w * hv;
    acc[4] += w1.x * hv; acc[5] += w1.y * hv; acc[6] += w1.z * hv; acc[7] += w1.w * hv;
  }
#pragma unroll
  for (int r = 0; r < 8; ++r) red[w][r][lane] = acc[r];
  __syncthreads();
#pragma unroll
  for (int rr = 0; rr < 2; ++rr) {
    int r = w * 2 + rr;
    y2[r][lane] = red[0][r][lane] + red[1][r][lane] + red[2][r][lane] + red[3][r][lane];
  }
  {
    float a0 = bgc2[lane], a1 = a0;
    for (int k = 0; k < Hh; ++k) {
      float wk = wgc2T[k * Hh + lane];
      a0 += wk * y2[w * 2 + 0][k];
      a1 += wk * y2[w * 2 + 1][k];
    }
    sf_s[w * 2 + 0][lane] = fmaxf(a0, 0.f);
    sf_s[w * 2 + 1][lane] = fmaxf(a1, 0.f);
  }

  float hn_reg[2];
  {
    float bi_r = bih[lane], bi_z = bih[64 + lane], bi_n = bih[128 + lane];
    float bh_r = bhh[lane], bh_z = bhh[64 + lane], bh_n = bhh[128 + lane];
    float gir[2], giz[2], gin[2], ghr[2], ghz[2], ghn[2];
#pragma unroll
    for (int rr = 0; rr < 2; ++rr) {
      gir[rr] = bi_r; giz[rr] = bi_z; gin[rr] = bi_n;
      ghr[rr] = bh_r; ghz[rr] = bh_z; ghn[rr] = bh_n;
    }
#pragma unroll 4
    for (int kb = 0; kb < 16; ++kb) {
      int k0 = kb * 4;
      float4 wi[4], wh[4];
#pragma unroll
      for (int q = 0; q < 4; ++q) {
        wi[q] = wihP[(k0 + q) * 64 + lane];
        wh[q] = whhP[(k0 + q) * 64 + lane];
      }
#pragma unroll
      for (int rr = 0; rr < 2; ++rr) {
        const float4 s4 = *(const float4*)&sf_s[w * 2 + rr][k0];
        const float4 h4 = *(const float4*)&h_s[w * 2 + rr][k0];
        gir[rr] += s4.x * wi[0].x + s4.y * wi[1].x + s4.z * wi[2].x + s4.w * wi[3].x;
        giz[rr] += s4.x * wi[0].y + s4.y * wi[1].y + s4.z * wi[2].y + s4.w * wi[3].y;
        gin[rr] += s4.x * wi[0].z + s4.y * wi[1].z + s4.z * wi[2].z + s4.w * wi[3].z;
        ghr[rr] += h4.x * wh[0].x + h4.y * wh[1].x + h4.z * wh[2].x + h4.w * wh[3].x;
        ghz[rr] += h4.x * wh[0].y + h4.y * wh[1].y + h4.z * wh[2].y + h4.w * wh[3].y;
        ghn[rr] += h4.x * wh[0].z + h4.y * wh[1].z + h4.z * wh[2].z + h4.w * wh[3].z;
      }
    }
#pragma unroll
    for (int rr = 0; rr < 2; ++rr) {
      float rg = 1.f / (1.f + expf(-(gir[rr] + ghr[rr])));
      float zg = 1.f / (1.f + expf(-(giz[rr] + ghz[rr])));
      float ng = tanhf(gin[rr] + rg * ghn[rr]);
      hn_reg[rr] = (1.f - zg) * ng + zg * hp_reg[rr];
      hstate[((long)b * Nn + i0 + w * 2 + rr) * Hh + lane] = hn_reg[rr];
      hn_lds[w * 2 + rr][lane] = hn_reg[rr];
    }
  }
  __syncthreads();
  {
    int row = tid >> 5, m = tid & 31;
    float um = bm1[m];
    for (int k = 0; k < Hh; ++k) um += wm1T[k * M1 + m] * hn_lds[row][k];
    u_lds[row][m] = fmaxf(um, 0.f);
  }
  __syncthreads();
  if (tid < 8 * Fp) {
    int row = tid / Fp, f = tid - row * Fp;
    float pf = bm2[f];
#pragma unroll
    for (int m = 0; m < M1; ++m) pf += wm2T[m * Fp + f] * u_lds[row][m];
    int i = i0 + row;
    outp[(((long)b * PredL + p) * Nn + i) * Fp + f] = pf;
    xnext[((long)b * Nn + i) * Fp + f] = pf;
  }
}

// ---------------------------------------------------------------------------
extern "C" void kernel_launch(void* const* d_in, const int* in_sizes, int n_in,
                              void* d_out, int out_size, void* d_ws, size_t ws_size,
                              hipStream_t stream) {
  const float* hp     = (const float*)d_in[0];
  const float* hw     = (const float*)d_in[1];
  const float* adj    = (const float*)d_in[2];
  const float* coords = (const float*)d_in[3];
  const float* wgc1   = (const float*)d_in[4];
  const float* bgc1   = (const float*)d_in[5];
  const float* wgc2   = (const float*)d_in[6];
  const float* bgc2   = (const float*)d_in[7];
  const float* wih    = (const float*)d_in[8];
  const float* whh    = (const float*)d_in[9];
  const float* bih    = (const float*)d_in[10];
  const float* bhh    = (const float*)d_in[11];
  const float* wm1    = (const float*)d_in[12];
  const float* bm1    = (const float*)d_in[13];
  const float* wm2    = (const float*)d_in[14];
  const float* bm2    = (const float*)d_in[15];
  float* out = (float*)d_out;

  float* w = (float*)d_ws;
  float2* pk    = (float2*)w; w += Nn * Nn * 2;
  float* d23    = w; w += Bsz * Nn;
  float* e23    = w; w += Bsz * Nn;
  float* hstate = w; w += Bsz * Nn * Hh;
  float* sf_all = w; w += (long)Tt * Bsz * Nn * Hh;
  float* gi_ch  = w; w += (long)TCHUNK * Bsz * Nn * 3 * 64;
  float* h1d    = w; w += Bsz * Nn * Hh;
  float* xb0    = w; w += Bsz * Nn * Fp;
  float* xb1    = w; w += Bsz * Nn * Fp;
  float* A1d    = w; w += Bsz * Nn * Nn;
  float* A2d    = w; w += Bsz * Nn * Nn;
  float* wgc2T  = w; w += Hh * Hh;
  float* wm1T   = w; w += Hh * M1;
  float* wm2T   = w; w += M1 * Fp;
  float4* wihP  = (float4*)w; w += Hh * 64 * 4;
  float4* whhP  = (float4*)w; w += Hh * 64 * 4;

  k_prep<<<Nn + 1, 256, 0, stream>>>(coords, adj, wgc2, wih, whh, wm1, wm2,
                                     pk, wgc2T, wm1T, wm2T, wihP, whhP);
  k_enc<<<Tt * Bsz, 256, 0, stream>>>(pk, hp, hw, wgc1, bgc1, wgc2T, bgc2,
                                      sf_all, d23, e23);
  for (int s = 0; s < Tt / TCHUNK; ++s) {
    int t0 = s * TCHUNK;
    k_gi<<<(TCHUNK * Bsz * Nn) / 64, 256, 0, stream>>>(sf_all, wihP, bih,
                                                       gi_ch, t0);
    k_gru_scan4<<<Bsz * 16, 256, 0, stream>>>(gi_ch, whhP, bhh, hstate,
                                              t0, TCHUNK);
  }
  k_misc<<<Bsz * Nn + Bsz * Nn / 16, 256, 0, stream>>>(
      hw, pk, d23, e23, A1d, A2d, hstate, wm1T, bm1, wm2T, bm2, xb0);

  for (int p = 0; p < PredL; ++p) {
    float* xin  = (p & 1) ? xb1 : xb0;
    float* xout = (p & 1) ? xb0 : xb1;
    k_dstep_A<<<Bsz * 32, 256, 0, stream>>>(xin, A1d, wgc1, bgc1, h1d);
    k_dstep_B<<<Bsz * 32, 256, 0, stream>>>(
        A2d, h1d, wgc2T, bgc2, wihP, whhP, bih, bhh, hstate,
        wm1T, bm1, wm2T, bm2, out, xout, p);
  }
}